// Round 1
// baseline (616.797 us; speedup 1.0000x reference)
//
#include <hip/hip_runtime.h>
#include <hip/hip_bf16.h>

typedef __attribute__((ext_vector_type(8))) short bv8;
typedef __attribute__((ext_vector_type(4))) float fv4;
typedef __hip_bfloat16 bf16;

#define MFMA16(a,b,c) __builtin_amdgcn_mfma_f32_16x16x32_bf16((a),(b),(c),0,0,0)

// ---------------- block reduce helpers ----------------
template<int NW>
__device__ __forceinline__ float blockReduceSumF(float v) {
  #pragma unroll
  for (int m = 1; m < 64; m <<= 1) v += __shfl_xor(v, m, 64);
  __shared__ float sm[NW];
  if ((threadIdx.x & 63) == 0) sm[threadIdx.x >> 6] = v;
  __syncthreads();
  float t = 0.f;
  #pragma unroll
  for (int i = 0; i < NW; ++i) t += sm[i];
  __syncthreads();
  return t;
}

template<int NW>
__device__ __forceinline__ double blockReduceSumD(double v) {
  #pragma unroll
  for (int m = 1; m < 64; m <<= 1) v += __shfl_xor(v, m, 64);
  __shared__ double sm[NW];
  if ((threadIdx.x & 63) == 0) sm[threadIdx.x >> 6] = v;
  __syncthreads();
  double t = 0.0;
  #pragma unroll
  for (int i = 0; i < NW; ++i) t += sm[i];
  __syncthreads();
  return t;
}

template<int NW>
__device__ __forceinline__ double blockReduceMaxD(double v) {
  #pragma unroll
  for (int m = 1; m < 64; m <<= 1) v = fmax(v, __shfl_xor(v, m, 64));
  __shared__ double sm[NW];
  if ((threadIdx.x & 63) == 0) sm[threadIdx.x >> 6] = v;
  __syncthreads();
  double t = sm[0];
  #pragma unroll
  for (int i = 1; i < NW; ++i) t = fmax(t, sm[i]);
  __syncthreads();
  return t;
}

// ---------------- small utility kernels ----------------
__global__ __launch_bounds__(256)
void cast_f2b_kernel(const float* __restrict__ src, bf16* __restrict__ dst, int n) {
  for (int i = blockIdx.x * 256 + threadIdx.x; i < n; i += gridDim.x * 256)
    dst[i] = __float2bfloat16(src[i]);
}

// LayerNorm of x rows -> bf16
__global__ __launch_bounds__(256)
void ln_kernel(const float* __restrict__ x, const float* __restrict__ w,
               const float* __restrict__ bb, bf16* __restrict__ out) {
  const int r = blockIdx.x;
  const float* xr = x + (size_t)r * 1024;
  float v4[4]; float s = 0.f;
  #pragma unroll
  for (int i = 0; i < 4; ++i) { v4[i] = xr[threadIdx.x + i * 256]; s += v4[i]; }
  s = blockReduceSumF<4>(s);
  const float mean = s * (1.0f / 1024.0f);
  float vs = 0.f;
  #pragma unroll
  for (int i = 0; i < 4; ++i) { float d = v4[i] - mean; vs += d * d; }
  vs = blockReduceSumF<4>(vs);
  const float rstd = 1.0f / sqrtf(vs * (1.0f / 1024.0f) + 1e-5f);
  bf16* orow = out + (size_t)r * 1024;
  #pragma unroll
  for (int i = 0; i < 4; ++i) {
    int d = threadIdx.x + i * 256;
    orow[d] = __float2bfloat16((v4[i] - mean) * rstd * w[d] + bb[d]);
  }
}

// s_q[r], s_kv[r] dot products in fp64
__global__ __launch_bounds__(256)
void sdot_kernel(const float* __restrict__ x, const float* __restrict__ rtq,
                 const float* __restrict__ rtkv, double* __restrict__ s) {
  const int r = blockIdx.x;
  const float* xr = x + (size_t)r * 1024;
  double sq = 0.0, sk = 0.0;
  #pragma unroll
  for (int i = 0; i < 4; ++i) {
    int d = threadIdx.x + i * 256;
    double xv = (double)xr[d];
    sq += xv * (double)rtq[d];
    sk += xv * (double)rtkv[d];
  }
  sq = blockReduceSumD<4>(sq);
  sk = blockReduceSumD<4>(sk);
  if (threadIdx.x == 0) { s[r] = sq; s[16384 + r] = sk; }
}

// 50 sinkhorn-ish iterations, fp64, one block per (route, batch)
__global__ __launch_bounds__(1024)
void route_iter_kernel(const double* __restrict__ s_all, float* __restrict__ scores_all) {
  const int route = blockIdx.x >> 2, b = blockIdx.x & 3;
  const double* s = s_all + route * 16384 + b * 4096;
  float* sc = scores_all + route * 16384 + b * 4096;
  const double logk = (route == 0) ? log(576.0) : log(1152.0);
  double sv[4], bb[4];
  #pragma unroll
  for (int i = 0; i < 4; ++i) { sv[i] = s[threadIdx.x + i * 1024]; bb[i] = -sv[i]; }
  double a = 0.0;
  for (int it = 0; it < 50; ++it) {
    double mx = -1e300;
    #pragma unroll
    for (int i = 0; i < 4; ++i) mx = fmax(mx, sv[i] + bb[i]);
    mx = blockReduceMaxD<16>(mx);
    double se = 0.0;
    #pragma unroll
    for (int i = 0; i < 4; ++i) se += exp(sv[i] + bb[i] - mx);
    se = blockReduceSumD<16>(se);
    a = logk - (log(se) + mx);
    #pragma unroll
    for (int i = 0; i < 4; ++i) bb[i] = -fmax(sv[i] + a, 0.0);
  }
  #pragma unroll
  for (int i = 0; i < 4; ++i)
    sc[threadIdx.x + i * 1024] = (float)exp(sv[i] + a + bb[i]);
}

// full bitonic sort per (route,batch); jax top_k tie-break = ascending index
__global__ __launch_bounds__(1024)
void topk_kernel(const float* __restrict__ scores, int* __restrict__ iq,
                 int* __restrict__ ikv, int* __restrict__ posq) {
  const int route = blockIdx.x >> 2, b = blockIdx.x & 3;
  const float* sc = scores + route * 16384 + b * 4096;
  __shared__ unsigned long long keys[4096];
  const int tid = threadIdx.x;
  for (int i = tid; i < 4096; i += 1024) {
    unsigned bits = __float_as_uint(sc[i]);   // scores >= 0 -> bits monotone
    keys[i] = ((unsigned long long)(~bits) << 32) | (unsigned long long)i;
  }
  for (int k = 2; k <= 4096; k <<= 1) {
    for (int j = k >> 1; j > 0; j >>= 1) {
      __syncthreads();
      for (int t = tid; t < 2048; t += 1024) {
        int i = ((t & ~(j - 1)) << 1) | (t & (j - 1));
        int ip = i + j;
        unsigned long long av = keys[i], bv = keys[ip];
        bool up = ((i & k) == 0);
        if (up ? (av > bv) : (av < bv)) { keys[i] = bv; keys[ip] = av; }
      }
    }
  }
  __syncthreads();
  if (route == 0) {
    for (int j = tid; j < 512; j += 1024) {
      int idx = (int)(keys[j] & 0xFFFFFFFFull);
      iq[b * 512 + j] = idx;
      posq[b * 4096 + idx] = j;
    }
  } else {
    for (int j = tid; j < 1024; j += 1024)
      ikv[b * 1024 + j] = (int)(keys[j] & 0xFFFFFFFFull);
  }
}

// gather selected tokens + RMS norm -> bf16
__global__ __launch_bounds__(256)
void gather_rms_kernel(const float* __restrict__ x, const float* __restrict__ gamma,
                       const int* __restrict__ iq, const int* __restrict__ ikv,
                       bf16* __restrict__ xq, bf16* __restrict__ xkv) {
  const int bid = blockIdx.x;
  const float* src; bf16* dst;
  if (bid < 2048) {
    int b = bid >> 9, j = bid & 511;
    int tok = iq[b * 512 + j];
    src = x + ((size_t)(b * 4096 + tok)) * 1024;
    dst = xq + (size_t)bid * 1024;
  } else {
    int id = bid - 2048;
    int b = id >> 10, j = id & 1023;
    int tok = ikv[b * 1024 + j];
    src = x + ((size_t)(b * 4096 + tok)) * 1024;
    dst = xkv + (size_t)id * 1024;
  }
  float v4[4]; float ss = 0.f;
  #pragma unroll
  for (int i = 0; i < 4; ++i) { v4[i] = src[threadIdx.x + i * 256]; ss += v4[i] * v4[i]; }
  ss = blockReduceSumF<4>(ss);
  const float nrm = fmaxf(sqrtf(ss), 1e-12f);
  const float scl = 32.0f / nrm;
  #pragma unroll
  for (int i = 0; i < 4; ++i) {
    int d = threadIdx.x + i * 256;
    dst[d] = __float2bfloat16(v4[i] * scl * gamma[d]);
  }
}

// ---------------- GEMM: C(MxN) = A(MxK) * B(NxK)^T, bf16 in, fp32 acc ----------------
// EPI: 0 = bf16 store, 1 = f32 store, 2 = f32 store + combine (light + heavy/null_q)
template<int EPI>
__global__ __launch_bounds__(256)
void gemm_bt(const bf16* __restrict__ A, const bf16* __restrict__ B, void* __restrict__ Cout,
             int M, int N, int K,
             const int* __restrict__ posq, const float* __restrict__ heavy,
             const float* __restrict__ nullq) {
  __shared__ bf16 As[128][40];
  __shared__ bf16 Bs[128][40];
  const int tid = threadIdx.x;
  const int lane = tid & 63, wv = tid >> 6;
  const int wr = wv >> 1, wc = wv & 1;
  const int lrow = lane & 15, lk = (lane >> 4) * 8;
  const int row0 = blockIdx.y * 128, col0 = blockIdx.x * 128;
  fv4 acc[4][4];
  #pragma unroll
  for (int m = 0; m < 4; ++m)
    #pragma unroll
    for (int n = 0; n < 4; ++n) acc[m][n] = (fv4){0.f, 0.f, 0.f, 0.f};
  for (int k0 = 0; k0 < K; k0 += 32) {
    #pragma unroll
    for (int v = 0; v < 2; ++v) {
      int vec = tid + v * 256;
      int r = vec >> 2, ko = (vec & 3) * 8;
      *(bv8*)&As[r][ko] = *(const bv8*)&A[(size_t)(row0 + r) * K + k0 + ko];
      *(bv8*)&Bs[r][ko] = *(const bv8*)&B[(size_t)(col0 + r) * K + k0 + ko];
    }
    __syncthreads();
    bv8 af[4], bfr[4];
    #pragma unroll
    for (int m = 0; m < 4; ++m) af[m] = *(bv8*)&As[wr * 64 + m * 16 + lrow][lk];
    #pragma unroll
    for (int n = 0; n < 4; ++n) bfr[n] = *(bv8*)&Bs[wc * 64 + n * 16 + lrow][lk];
    #pragma unroll
    for (int m = 0; m < 4; ++m)
      #pragma unroll
      for (int n = 0; n < 4; ++n)
        acc[m][n] = MFMA16(af[m], bfr[n], acc[m][n]);
    __syncthreads();
  }
  #pragma unroll
  for (int m = 0; m < 4; ++m) {
    int gr0 = row0 + wr * 64 + m * 16 + (lane >> 4) * 4;
    #pragma unroll
    for (int n = 0; n < 4; ++n) {
      int gc = col0 + wc * 64 + n * 16 + lrow;
      #pragma unroll
      for (int r = 0; r < 4; ++r) {
        int grow = gr0 + r;
        float vv = acc[m][n][r];
        if (EPI == 0) {
          ((bf16*)Cout)[(size_t)grow * N + gc] = __float2bfloat16(vv);
        } else if (EPI == 1) {
          ((float*)Cout)[(size_t)grow * N + gc] = vv;
        } else {
          int p = posq[grow];
          float add = (p >= 0) ? heavy[((size_t)((grow >> 12) * 512 + p)) * 1024 + gc]
                               : nullq[gc];
          ((float*)Cout)[(size_t)grow * N + gc] = vv + add;
        }
      }
    }
  }
}

// ---------------- local windowed attention (flash over 3 windows) ----------------
__global__ __launch_bounds__(256)
void local_attn_kernel(const bf16* __restrict__ qkv, bf16* __restrict__ olight) {
  const int w = blockIdx.x, h = blockIdx.y, b = blockIdx.z;
  const int tid = threadIdx.x;
  const int lane = tid & 63, wv = tid >> 6;
  const int lrow = lane & 15, lkg = lane >> 4;
  __shared__ bf16 Qs[64][72], Ks[64][72], Vts[64][72], Ps[64][72];
  {
    const size_t baseq = ((size_t)(b * 4096 + w * 64)) * 1536 + h * 64;
    #pragma unroll
    for (int v = 0; v < 2; ++v) {
      int vec = tid + v * 256; int i = vec >> 3, dd = (vec & 7) * 8;
      *(bv8*)&Qs[i][dd] = *(const bv8*)&qkv[baseq + (size_t)i * 1536 + dd];
    }
  }
  fv4 oacc[4];
  float m_run[4], l_run[4];
  #pragma unroll
  for (int n = 0; n < 4; ++n) oacc[n] = (fv4){0.f, 0.f, 0.f, 0.f};
  #pragma unroll
  for (int r = 0; r < 4; ++r) { m_run[r] = -INFINITY; l_run[r] = 0.f; }
  for (int c = 0; c < 3; ++c) {
    int sw = w - 1 + c;
    if (sw < 0 || sw >= 64) continue;           // uniform across block
    __syncthreads();
    const size_t bkv = ((size_t)(b * 4096 + sw * 64)) * 1536 + h * 64;
    #pragma unroll
    for (int v = 0; v < 2; ++v) {
      int vec = tid + v * 256; int i = vec >> 3, dd = (vec & 7) * 8;
      *(bv8*)&Ks[i][dd] = *(const bv8*)&qkv[bkv + 512 + (size_t)i * 1536 + dd];
    }
    for (int e = tid; e < 4096; e += 256) {
      int j = e >> 6, dd = e & 63;
      Vts[dd][j] = qkv[bkv + 1024 + (size_t)j * 1536 + dd];
    }
    __syncthreads();
    fv4 sa[4];
    #pragma unroll
    for (int n = 0; n < 4; ++n) {
      sa[n] = (fv4){0.f, 0.f, 0.f, 0.f};
      #pragma unroll
      for (int ks = 0; ks < 2; ++ks) {
        bv8 aq = *(bv8*)&Qs[wv * 16 + lrow][lkg * 8 + ks * 32];
        bv8 bk = *(bv8*)&Ks[n * 16 + lrow][lkg * 8 + ks * 32];
        sa[n] = MFMA16(aq, bk, sa[n]);
      }
    }
    float mc[4];
    #pragma unroll
    for (int r = 0; r < 4; ++r) {
      #pragma unroll
      for (int n = 0; n < 4; ++n) sa[n][r] *= 0.125f;
      mc[r] = fmaxf(fmaxf(sa[0][r], sa[1][r]), fmaxf(sa[2][r], sa[3][r]));
    }
    #pragma unroll
    for (int m = 1; m < 16; m <<= 1)
      #pragma unroll
      for (int r = 0; r < 4; ++r) mc[r] = fmaxf(mc[r], __shfl_xor(mc[r], m, 64));
    float p[4][4], ls[4];
    #pragma unroll
    for (int r = 0; r < 4; ++r) {
      float mn = fmaxf(m_run[r], mc[r]);
      float scl = expf(m_run[r] - mn);
      ls[r] = 0.f;
      #pragma unroll
      for (int n = 0; n < 4; ++n) { p[n][r] = expf(sa[n][r] - mn); ls[r] += p[n][r]; }
      m_run[r] = mn;
      l_run[r] *= scl;
      #pragma unroll
      for (int n = 0; n < 4; ++n) oacc[n][r] *= scl;
    }
    #pragma unroll
    for (int m = 1; m < 16; m <<= 1)
      #pragma unroll
      for (int r = 0; r < 4; ++r) ls[r] += __shfl_xor(ls[r], m, 64);
    #pragma unroll
    for (int r = 0; r < 4; ++r) l_run[r] += ls[r];
    #pragma unroll
    for (int n = 0; n < 4; ++n)
      #pragma unroll
      for (int r = 0; r < 4; ++r)
        Ps[wv * 16 + lkg * 4 + r][n * 16 + lrow] = __float2bfloat16(p[n][r]);
    __syncthreads();
    #pragma unroll
    for (int n = 0; n < 4; ++n)
      #pragma unroll
      for (int ks = 0; ks < 2; ++ks) {
        bv8 ap = *(bv8*)&Ps[wv * 16 + lrow][lkg * 8 + ks * 32];
        bv8 bvv = *(bv8*)&Vts[n * 16 + lrow][lkg * 8 + ks * 32];
        oacc[n] = MFMA16(ap, bvv, oacc[n]);
      }
  }
  const size_t ob = ((size_t)(b * 4096 + w * 64 + wv * 16)) * 512 + h * 64;
  #pragma unroll
  for (int n = 0; n < 4; ++n)
    #pragma unroll
    for (int r = 0; r < 4; ++r) {
      int row = lkg * 4 + r;
      olight[ob + (size_t)row * 512 + n * 16 + lrow] = __float2bfloat16(oacc[n][r] / l_run[r]);
    }
}

// ---------------- heavy attention (flash over 1025 kv incl. null) ----------------
__global__ __launch_bounds__(256)
void heavy_attn_kernel(const bf16* __restrict__ qh, const bf16* __restrict__ kvh,
                       const float* __restrict__ nkv, bf16* __restrict__ oheavy) {
  const int qt = blockIdx.x, h = blockIdx.y, b = blockIdx.z;
  const int tid = threadIdx.x;
  const int lane = tid & 63, wv = tid >> 6;
  const int lrow = lane & 15, lkg = lane >> 4;
  __shared__ bf16 Qs[64][72], Ks[64][72], Vts[64][72], Ps[64][72];
  {
    const size_t baseq = ((size_t)(b * 512 + qt * 64)) * 512 + h * 64;
    #pragma unroll
    for (int v = 0; v < 2; ++v) {
      int vec = tid + v * 256; int i = vec >> 3, dd = (vec & 7) * 8;
      *(bv8*)&Qs[i][dd] = *(const bv8*)&qh[baseq + (size_t)i * 512 + dd];
    }
  }
  fv4 oacc[4];
  float m_run[4], l_run[4];
  #pragma unroll
  for (int n = 0; n < 4; ++n) oacc[n] = (fv4){0.f, 0.f, 0.f, 0.f};
  #pragma unroll
  for (int r = 0; r < 4; ++r) { m_run[r] = -INFINITY; l_run[r] = 0.f; }
  for (int c = 0; c < 17; ++c) {
    __syncthreads();
    #pragma unroll
    for (int v = 0; v < 2; ++v) {
      int vec = tid + v * 256; int j = vec >> 3, dd = (vec & 7) * 8;
      int kvg = c * 64 + j;
      bv8 val;
      if (kvg >= 1 && kvg <= 1024) {
        val = *(const bv8*)&kvh[((size_t)(b * 1024 + kvg - 1)) * 1024 + h * 128 + dd];
      } else if (kvg == 0) {
        #pragma unroll
        for (int t = 0; t < 8; ++t) ((bf16*)&val)[t] = __float2bfloat16(nkv[h * 64 + dd + t]);
      } else {
        #pragma unroll
        for (int t = 0; t < 8; ++t) ((short*)&val)[t] = 0;
      }
      *(bv8*)&Ks[j][dd] = val;
    }
    for (int e = tid; e < 4096; e += 256) {
      int j = e >> 6, dd = e & 63;
      int kvg = c * 64 + j;
      bf16 vvv;
      if (kvg >= 1 && kvg <= 1024)
        vvv = kvh[((size_t)(b * 1024 + kvg - 1)) * 1024 + h * 128 + 64 + dd];
      else if (kvg == 0)
        vvv = __float2bfloat16(nkv[512 + h * 64 + dd]);
      else
        vvv = __float2bfloat16(0.0f);
      Vts[dd][j] = vvv;
    }
    __syncthreads();
    fv4 sa[4];
    #pragma unroll
    for (int n = 0; n < 4; ++n) {
      sa[n] = (fv4){0.f, 0.f, 0.f, 0.f};
      #pragma unroll
      for (int ks = 0; ks < 2; ++ks) {
        bv8 aq = *(bv8*)&Qs[wv * 16 + lrow][lkg * 8 + ks * 32];
        bv8 bk = *(bv8*)&Ks[n * 16 + lrow][lkg * 8 + ks * 32];
        sa[n] = MFMA16(aq, bk, sa[n]);
      }
    }
    float mc[4];
    #pragma unroll
    for (int r = 0; r < 4; ++r) {
      #pragma unroll
      for (int n = 0; n < 4; ++n) {
        sa[n][r] *= 0.125f;
        int kvg = c * 64 + n * 16 + lrow;
        if (kvg > 1024) sa[n][r] = -1e30f;
      }
      mc[r] = fmaxf(fmaxf(sa[0][r], sa[1][r]), fmaxf(sa[2][r], sa[3][r]));
    }
    #pragma unroll
    for (int m = 1; m < 16; m <<= 1)
      #pragma unroll
      for (int r = 0; r < 4; ++r) mc[r] = fmaxf(mc[r], __shfl_xor(mc[r], m, 64));
    float p[4][4], ls[4];
    #pragma unroll
    for (int r = 0; r < 4; ++r) {
      float mn = fmaxf(m_run[r], mc[r]);
      float scl = expf(m_run[r] - mn);
      ls[r] = 0.f;
      #pragma unroll
      for (int n = 0; n < 4; ++n) { p[n][r] = expf(sa[n][r] - mn); ls[r] += p[n][r]; }
      m_run[r] = mn;
      l_run[r] *= scl;
      #pragma unroll
      for (int n = 0; n < 4; ++n) oacc[n][r] *= scl;
    }
    #pragma unroll
    for (int m = 1; m < 16; m <<= 1)
      #pragma unroll
      for (int r = 0; r < 4; ++r) ls[r] += __shfl_xor(ls[r], m, 64);
    #pragma unroll
    for (int r = 0; r < 4; ++r) l_run[r] += ls[r];
    #pragma unroll
    for (int n = 0; n < 4; ++n)
      #pragma unroll
      for (int r = 0; r < 4; ++r)
        Ps[wv * 16 + lkg * 4 + r][n * 16 + lrow] = __float2bfloat16(p[n][r]);
    __syncthreads();
    #pragma unroll
    for (int n = 0; n < 4; ++n)
      #pragma unroll
      for (int ks = 0; ks < 2; ++ks) {
        bv8 ap = *(bv8*)&Ps[wv * 16 + lrow][lkg * 8 + ks * 32];
        bv8 bvv = *(bv8*)&Vts[n * 16 + lrow][lkg * 8 + ks * 32];
        oacc[n] = MFMA16(ap, bvv, oacc[n]);
      }
  }
  const size_t ob = ((size_t)(b * 512 + qt * 64 + wv * 16)) * 512 + h * 64;
  #pragma unroll
  for (int n = 0; n < 4; ++n)
    #pragma unroll
    for (int r = 0; r < 4; ++r) {
      int row = lkg * 4 + r;
      oheavy[ob + (size_t)row * 512 + n * 16 + lrow] = __float2bfloat16(oacc[n][r] / l_run[r]);
    }
}

// ---------------- launcher ----------------
extern "C" void kernel_launch(void* const* d_in, const int* in_sizes, int n_in,
                              void* d_out, int out_size, void* d_ws, size_t ws_size,
                              hipStream_t stream) {
  (void)in_sizes; (void)n_in; (void)out_size; (void)ws_size;
  const float* x     = (const float*)d_in[0];
  const float* ln_w  = (const float*)d_in[1];
  const float* ln_b  = (const float*)d_in[2];
  const float* Wqkv  = (const float*)d_in[3];
  const float* Woutl = (const float*)d_in[4];
  const float* rtq   = (const float*)d_in[5];
  const float* rtkv  = (const float*)d_in[6];
  const float* gamma = (const float*)d_in[7];
  const float* Wq    = (const float*)d_in[8];
  const float* Wkv   = (const float*)d_in[9];
  const float* Wouth = (const float*)d_in[10];
  const float* nkv   = (const float*)d_in[11];
  const float* nq    = (const float*)d_in[12];
  float* out = (float*)d_out;

  char* ws = (char*)d_ws;
  size_t off = 0;
  auto alloc = [&](size_t bytes) -> void* {
    void* p = ws + off;
    off = (off + bytes + 255) & ~(size_t)255;
    return p;
  };
  bf16* ln_bf    = (bf16*)alloc(16384ull * 1024 * 2);
  bf16* qkv_bf   = (bf16*)alloc(16384ull * 1536 * 2);
  bf16* ol_bf    = (bf16*)alloc(16384ull * 512 * 2);
  bf16* Wqkv_bf  = (bf16*)alloc(1536ull * 1024 * 2);
  bf16* Woutl_bf = (bf16*)alloc(1024ull * 512 * 2);
  bf16* Wq_bf    = (bf16*)alloc(512ull * 1024 * 2);
  bf16* Wkv_bf   = (bf16*)alloc(1024ull * 1024 * 2);
  bf16* Wouth_bf = (bf16*)alloc(1024ull * 512 * 2);
  double* s_d    = (double*)alloc(32768ull * 8);
  float* scores  = (float*)alloc(32768ull * 4);
  int* iq        = (int*)alloc(2048ull * 4);
  int* ikv       = (int*)alloc(4096ull * 4);
  int* posq      = (int*)alloc(16384ull * 4);
  bf16* xq_bf    = (bf16*)alloc(2048ull * 1024 * 2);
  bf16* xkv_bf   = (bf16*)alloc(4096ull * 1024 * 2);
  bf16* qh_bf    = (bf16*)alloc(2048ull * 512 * 2);
  bf16* kvh_bf   = (bf16*)alloc(4096ull * 1024 * 2);
  bf16* oh_bf    = (bf16*)alloc(2048ull * 512 * 2);
  float* heavy_f = (float*)alloc(2048ull * 1024 * 4);

  // weight casts
  cast_f2b_kernel<<<512, 256, 0, stream>>>(Wqkv,  Wqkv_bf,  1536 * 1024);
  cast_f2b_kernel<<<512, 256, 0, stream>>>(Woutl, Woutl_bf, 1024 * 512);
  cast_f2b_kernel<<<512, 256, 0, stream>>>(Wq,    Wq_bf,    512 * 1024);
  cast_f2b_kernel<<<512, 256, 0, stream>>>(Wkv,   Wkv_bf,   1024 * 1024);
  cast_f2b_kernel<<<512, 256, 0, stream>>>(Wouth, Wouth_bf, 1024 * 512);

  // routing
  ln_kernel<<<16384, 256, 0, stream>>>(x, ln_w, ln_b, ln_bf);
  sdot_kernel<<<16384, 256, 0, stream>>>(x, rtq, rtkv, s_d);
  route_iter_kernel<<<8, 1024, 0, stream>>>(s_d, scores);
  hipMemsetAsync(posq, 0xFF, 16384 * 4, stream);
  topk_kernel<<<8, 1024, 0, stream>>>(scores, iq, ikv, posq);

  // light path
  gemm_bt<0><<<dim3(12, 128), 256, 0, stream>>>(ln_bf, Wqkv_bf, qkv_bf, 16384, 1536, 1024,
                                                nullptr, nullptr, nullptr);
  local_attn_kernel<<<dim3(64, 8, 4), 256, 0, stream>>>(qkv_bf, ol_bf);

  // heavy path
  gather_rms_kernel<<<6144, 256, 0, stream>>>(x, gamma, iq, ikv, xq_bf, xkv_bf);
  gemm_bt<0><<<dim3(4, 16), 256, 0, stream>>>(xq_bf, Wq_bf, qh_bf, 2048, 512, 1024,
                                              nullptr, nullptr, nullptr);
  gemm_bt<0><<<dim3(8, 32), 256, 0, stream>>>(xkv_bf, Wkv_bf, kvh_bf, 4096, 1024, 1024,
                                              nullptr, nullptr, nullptr);
  heavy_attn_kernel<<<dim3(8, 8, 4), 256, 0, stream>>>(qh_bf, kvh_bf, nkv, oh_bf);
  gemm_bt<1><<<dim3(8, 16), 256, 0, stream>>>(oh_bf, Wouth_bf, heavy_f, 2048, 1024, 512,
                                              nullptr, nullptr, nullptr);

  // light output GEMM + fused combine (heavy scatter / null_q) -> d_out
  gemm_bt<2><<<dim3(8, 128), 256, 0, stream>>>(ol_bf, Woutl_bf, out, 16384, 1024, 512,
                                               posq, heavy_f, nq);
}

// Round 2
// 501.364 us; speedup vs baseline: 1.2302x; 1.2302x over previous
//
#include <hip/hip_runtime.h>
#include <hip/hip_bf16.h>

typedef __attribute__((ext_vector_type(8))) short bv8;
typedef __attribute__((ext_vector_type(4))) float fv4;
typedef __hip_bfloat16 bf16;

#define MFMA16(a,b,c) __builtin_amdgcn_mfma_f32_16x16x32_bf16((a),(b),(c),0,0,0)
#define GLOAD_LDS(gp, lp) __builtin_amdgcn_global_load_lds( \
    (const __attribute__((address_space(1))) void*)(gp), \
    (__attribute__((address_space(3))) void*)(lp), 16, 0, 0)

// ---------------- block reduce helpers ----------------
template<int NW>
__device__ __forceinline__ float blockReduceSumF(float v) {
  #pragma unroll
  for (int m = 1; m < 64; m <<= 1) v += __shfl_xor(v, m, 64);
  __shared__ float sm[NW];
  if ((threadIdx.x & 63) == 0) sm[threadIdx.x >> 6] = v;
  __syncthreads();
  float t = 0.f;
  #pragma unroll
  for (int i = 0; i < NW; ++i) t += sm[i];
  __syncthreads();
  return t;
}

template<int NW>
__device__ __forceinline__ double blockReduceSumD(double v) {
  #pragma unroll
  for (int m = 1; m < 64; m <<= 1) v += __shfl_xor(v, m, 64);
  __shared__ double sm[NW];
  if ((threadIdx.x & 63) == 0) sm[threadIdx.x >> 6] = v;
  __syncthreads();
  double t = 0.0;
  #pragma unroll
  for (int i = 0; i < NW; ++i) t += sm[i];
  __syncthreads();
  return t;
}

template<int NW>
__device__ __forceinline__ double blockReduceMaxD(double v) {
  #pragma unroll
  for (int m = 1; m < 64; m <<= 1) v = fmax(v, __shfl_xor(v, m, 64));
  __shared__ double sm[NW];
  if ((threadIdx.x & 63) == 0) sm[threadIdx.x >> 6] = v;
  __syncthreads();
  double t = sm[0];
  #pragma unroll
  for (int i = 1; i < NW; ++i) t = fmax(t, sm[i]);
  __syncthreads();
  return t;
}

// ---------------- small utility kernels ----------------
__global__ __launch_bounds__(256)
void cast_f2b_kernel(const float* __restrict__ src, bf16* __restrict__ dst, int n) {
  for (int i = blockIdx.x * 256 + threadIdx.x; i < n; i += gridDim.x * 256)
    dst[i] = __float2bfloat16(src[i]);
}

// Fused LayerNorm (-> bf16) + routing dot products (fp64)
__global__ __launch_bounds__(256)
void ln_sdot_kernel(const float* __restrict__ x, const float* __restrict__ w,
                    const float* __restrict__ bb, const float* __restrict__ rtq,
                    const float* __restrict__ rtkv, bf16* __restrict__ out,
                    double* __restrict__ s) {
  const int r = blockIdx.x;
  const float* xr = x + (size_t)r * 1024;
  float v4[4]; float ssum = 0.f;
  double dq = 0.0, dk = 0.0;
  #pragma unroll
  for (int i = 0; i < 4; ++i) {
    int d = threadIdx.x + i * 256;
    float v = xr[d];
    v4[i] = v; ssum += v;
    dq += (double)v * (double)rtq[d];
    dk += (double)v * (double)rtkv[d];
  }
  ssum = blockReduceSumF<4>(ssum);
  const float mean = ssum * (1.0f / 1024.0f);
  float vs = 0.f;
  #pragma unroll
  for (int i = 0; i < 4; ++i) { float d = v4[i] - mean; vs += d * d; }
  vs = blockReduceSumF<4>(vs);
  const float rstd = 1.0f / sqrtf(vs * (1.0f / 1024.0f) + 1e-5f);
  dq = blockReduceSumD<4>(dq);
  dk = blockReduceSumD<4>(dk);
  if (threadIdx.x == 0) { s[r] = dq; s[16384 + r] = dk; }
  bf16* orow = out + (size_t)r * 1024;
  #pragma unroll
  for (int i = 0; i < 4; ++i) {
    int d = threadIdx.x + i * 256;
    orow[d] = __float2bfloat16((v4[i] - mean) * rstd * w[d] + bb[d]);
  }
}

// Fused routing: 50 fixed-point iterations (closed form via precomputed exp)
// + threshold selection (prefix scan fast path; bitonic fallback).
__global__ __launch_bounds__(1024)
void route_sel_kernel(const double* __restrict__ s_all, int* __restrict__ iq,
                      int* __restrict__ ikv, int* __restrict__ posq) {
  const int route = blockIdx.x >> 2, b = blockIdx.x & 3;
  const double* s = s_all + route * 16384 + b * 4096;
  const double logk = (route == 0) ? log(576.0) : log(1152.0);
  const int KSEL = (route == 0) ? 512 : 1024;
  const int tid = threadIdx.x;
  const int lane = tid & 63, wid = tid >> 6;
  double sv[4], ev[4];
  #pragma unroll
  for (int i = 0; i < 4; ++i) sv[i] = s[tid * 4 + i];
  double mx = fmax(fmax(sv[0], sv[1]), fmax(sv[2], sv[3]));
  mx = blockReduceMaxD<16>(mx);
  #pragma unroll
  for (int i = 0; i < 4; ++i) ev[i] = exp(sv[i] - mx);
  __shared__ double red[32];
  __shared__ double a_sh;
  double a = logk - log(4096.0);   // iteration 1 (bb = -s  =>  logsumexp = log(4096))
  for (int it = 1; it < 50; ++it) {
    const double T = -a;
    double cnt = 0.0, us = 0.0;
    #pragma unroll
    for (int i = 0; i < 4; ++i) {
      if (sv[i] >= T) cnt += 1.0; else us += ev[i];
    }
    #pragma unroll
    for (int m = 1; m < 64; m <<= 1) { cnt += __shfl_xor(cnt, m, 64); us += __shfl_xor(us, m, 64); }
    if (lane == 0) { red[wid] = cnt; red[16 + wid] = us; }
    __syncthreads();
    if (tid == 0) {
      double tc = 0.0, tu = 0.0;
      #pragma unroll
      for (int i = 0; i < 16; ++i) { tc += red[i]; tu += red[16 + i]; }
      double se = tc * exp(T - mx) + tu;
      a_sh = logk - (mx + log(se));
    }
    __syncthreads();
    a = a_sh;
  }
  // final scores (fp32, matching reference semantics incl. rounding-to-1.0f ties)
  float scf[4]; int m4 = 0;
  #pragma unroll
  for (int i = 0; i < 4; ++i) {
    double v = sv[i] + a;
    scf[i] = (float)exp(fmin(v, 0.0));
    m4 += (scf[i] == 1.0f) ? 1 : 0;
  }
  __shared__ int scn[1024];
  scn[tid] = m4;
  __syncthreads();
  for (int off = 1; off < 1024; off <<= 1) {
    int v = (tid >= off) ? scn[tid - off] : 0;
    __syncthreads();
    scn[tid] += v;
    __syncthreads();
  }
  const int total = scn[1023];
  const int excl = scn[tid] - m4;
  if (total >= KSEL) {
    // fast path: top-K = first K saturated (score==1.0f) in ascending index order
    int rk = excl;
    #pragma unroll
    for (int i = 0; i < 4; ++i) {
      if (scf[i] == 1.0f) {
        if (rk < KSEL) {
          int idx = tid * 4 + i;
          if (route == 0) { iq[b * 512 + rk] = idx; posq[b * 4096 + idx] = rk; }
          else            { ikv[b * 1024 + rk] = idx; }
        }
        rk++;
      }
    }
  } else {
    // fallback: full bitonic sort (score desc, index asc) — replicates R1 topk
    __shared__ unsigned long long keys[4096];
    #pragma unroll
    for (int i = 0; i < 4; ++i) {
      unsigned bits = __float_as_uint(scf[i]);   // scores in [0,1] -> bits monotone
      keys[tid * 4 + i] = ((unsigned long long)(~bits) << 32) | (unsigned long long)(tid * 4 + i);
    }
    for (int k = 2; k <= 4096; k <<= 1) {
      for (int j = k >> 1; j > 0; j >>= 1) {
        __syncthreads();
        for (int t = tid; t < 2048; t += 1024) {
          int i2 = ((t & ~(j - 1)) << 1) | (t & (j - 1));
          int ip = i2 + j;
          unsigned long long av = keys[i2], bvv = keys[ip];
          bool up = ((i2 & k) == 0);
          if (up ? (av > bvv) : (av < bvv)) { keys[i2] = bvv; keys[ip] = av; }
        }
      }
    }
    __syncthreads();
    for (int j2 = tid; j2 < KSEL; j2 += 1024) {
      int idx = (int)(keys[j2] & 0xFFFFFFFFull);
      if (route == 0) { iq[b * 512 + j2] = idx; posq[b * 4096 + idx] = j2; }
      else            { ikv[b * 1024 + j2] = idx; }
    }
  }
}

// gather selected tokens + RMS norm -> bf16
__global__ __launch_bounds__(256)
void gather_rms_kernel(const float* __restrict__ x, const float* __restrict__ gamma,
                       const int* __restrict__ iq, const int* __restrict__ ikv,
                       bf16* __restrict__ xq, bf16* __restrict__ xkv) {
  const int bid = blockIdx.x;
  const float* src; bf16* dst;
  if (bid < 2048) {
    int b = bid >> 9, j = bid & 511;
    int tok = iq[b * 512 + j];
    src = x + ((size_t)(b * 4096 + tok)) * 1024;
    dst = xq + (size_t)bid * 1024;
  } else {
    int id = bid - 2048;
    int b = id >> 10, j = id & 1023;
    int tok = ikv[b * 1024 + j];
    src = x + ((size_t)(b * 4096 + tok)) * 1024;
    dst = xkv + (size_t)id * 1024;
  }
  float v4[4]; float ss = 0.f;
  #pragma unroll
  for (int i = 0; i < 4; ++i) { v4[i] = src[threadIdx.x + i * 256]; ss += v4[i] * v4[i]; }
  ss = blockReduceSumF<4>(ss);
  const float nrm = fmaxf(sqrtf(ss), 1e-12f);
  const float scl = 32.0f / nrm;
  #pragma unroll
  for (int i = 0; i < 4; ++i) {
    int d = threadIdx.x + i * 256;
    dst[d] = __float2bfloat16(v4[i] * scl * gamma[d]);
  }
}

// ---------------- GEMM: C(MxN) = A(MxK) * B(NxK)^T, bf16 in, fp32 acc ----------------
// m97-style: linear [128][32] LDS tiles staged via global_load_lds width 16.
// EPI: 0 = bf16 store, 1 = f32 store, 2 = f32 store + combine (light + heavy/null_q)
template<int EPI>
__global__ __launch_bounds__(256)
void gemm_bt(const bf16* __restrict__ A, const bf16* __restrict__ B, void* __restrict__ Cout,
             int M, int N, int K,
             const int* __restrict__ posq, const float* __restrict__ heavy,
             const float* __restrict__ nullq) {
  __shared__ alignas(16) bf16 As[128 * 32];
  __shared__ alignas(16) bf16 Bs[128 * 32];
  const int tid = threadIdx.x;
  const int lane = tid & 63, w = tid >> 6;
  const int wr = w >> 1, wc = w & 1;
  const int lrow = lane & 15, lk = (lane >> 4) * 8;
  const int row0 = blockIdx.y * 128, col0 = blockIdx.x * 128;
  fv4 acc[4][4];
  #pragma unroll
  for (int m = 0; m < 4; ++m)
    #pragma unroll
    for (int n = 0; n < 4; ++n) acc[m][n] = (fv4){0.f, 0.f, 0.f, 0.f};
  // per-lane staging source mapping (LDS linear: byte off = r*64 + c*16)
  const int ob0 = w * 2048;
  for (int k0 = 0; k0 < K; k0 += 32) {
    #pragma unroll
    for (int t = 0; t < 2; ++t) {
      int ob = ob0 + t * 1024;
      int ofl = ob + lane * 16;
      int r = ofl >> 6, c8 = ((ofl >> 4) & 3) * 8;
      GLOAD_LDS(A + (size_t)(row0 + r) * K + k0 + c8, (char*)As + ob);
      GLOAD_LDS(B + (size_t)(col0 + r) * K + k0 + c8, (char*)Bs + ob);
    }
    __syncthreads();   // drains vmcnt -> LDS tiles ready
    bv8 af[4], bfr[4];
    #pragma unroll
    for (int m = 0; m < 4; ++m) af[m] = *(bv8*)&As[(wr * 64 + m * 16 + lrow) * 32 + lk];
    #pragma unroll
    for (int n = 0; n < 4; ++n) bfr[n] = *(bv8*)&Bs[(wc * 64 + n * 16 + lrow) * 32 + lk];
    #pragma unroll
    for (int m = 0; m < 4; ++m)
      #pragma unroll
      for (int n = 0; n < 4; ++n)
        acc[m][n] = MFMA16(af[m], bfr[n], acc[m][n]);
    __syncthreads();
  }
  #pragma unroll
  for (int m = 0; m < 4; ++m) {
    int gr0 = row0 + wr * 64 + m * 16 + (lane >> 4) * 4;
    #pragma unroll
    for (int n = 0; n < 4; ++n) {
      int gc = col0 + wc * 64 + n * 16 + lrow;
      #pragma unroll
      for (int r = 0; r < 4; ++r) {
        int grow = gr0 + r;
        float vv = acc[m][n][r];
        if (EPI == 0) {
          ((bf16*)Cout)[(size_t)grow * N + gc] = __float2bfloat16(vv);
        } else if (EPI == 1) {
          ((float*)Cout)[(size_t)grow * N + gc] = vv;
        } else {
          int p = posq[grow];
          float add = (p >= 0) ? heavy[((size_t)((grow >> 12) * 512 + p)) * 1024 + gc]
                               : nullq[gc];
          ((float*)Cout)[(size_t)grow * N + gc] = vv + add;
        }
      }
    }
  }
}

// ---------------- local windowed attention (flash over 3 windows) ----------------
__global__ __launch_bounds__(256)
void local_attn_kernel(const bf16* __restrict__ qkv, bf16* __restrict__ olight) {
  const int w = blockIdx.x, h = blockIdx.y, b = blockIdx.z;
  const int tid = threadIdx.x;
  const int lane = tid & 63, wv = tid >> 6;
  const int lrow = lane & 15, lkg = lane >> 4;
  __shared__ bf16 Qs[64][72], Ks[64][72], Vts[64][72], Ps[64][72];
  {
    const size_t baseq = ((size_t)(b * 4096 + w * 64)) * 1536 + h * 64;
    #pragma unroll
    for (int v = 0; v < 2; ++v) {
      int vec = tid + v * 256; int i = vec >> 3, dd = (vec & 7) * 8;
      *(bv8*)&Qs[i][dd] = *(const bv8*)&qkv[baseq + (size_t)i * 1536 + dd];
    }
  }
  fv4 oacc[4];
  float m_run[4], l_run[4];
  #pragma unroll
  for (int n = 0; n < 4; ++n) oacc[n] = (fv4){0.f, 0.f, 0.f, 0.f};
  #pragma unroll
  for (int r = 0; r < 4; ++r) { m_run[r] = -INFINITY; l_run[r] = 0.f; }
  for (int c = 0; c < 3; ++c) {
    int sw = w - 1 + c;
    if (sw < 0 || sw >= 64) continue;           // uniform across block
    __syncthreads();
    const size_t bkv = ((size_t)(b * 4096 + sw * 64)) * 1536 + h * 64;
    #pragma unroll
    for (int v = 0; v < 2; ++v) {
      int vec = tid + v * 256; int i = vec >> 3, dd = (vec & 7) * 8;
      *(bv8*)&Ks[i][dd] = *(const bv8*)&qkv[bkv + 512 + (size_t)i * 1536 + dd];
    }
    for (int e = tid; e < 4096; e += 256) {
      int j = e >> 6, dd = e & 63;
      Vts[dd][j] = qkv[bkv + 1024 + (size_t)j * 1536 + dd];
    }
    __syncthreads();
    fv4 sa[4];
    #pragma unroll
    for (int n = 0; n < 4; ++n) {
      sa[n] = (fv4){0.f, 0.f, 0.f, 0.f};
      #pragma unroll
      for (int ks = 0; ks < 2; ++ks) {
        bv8 aq = *(bv8*)&Qs[wv * 16 + lrow][lkg * 8 + ks * 32];
        bv8 bk = *(bv8*)&Ks[n * 16 + lrow][lkg * 8 + ks * 32];
        sa[n] = MFMA16(aq, bk, sa[n]);
      }
    }
    float mc[4];
    #pragma unroll
    for (int r = 0; r < 4; ++r) {
      #pragma unroll
      for (int n = 0; n < 4; ++n) sa[n][r] *= 0.125f;
      mc[r] = fmaxf(fmaxf(sa[0][r], sa[1][r]), fmaxf(sa[2][r], sa[3][r]));
    }
    #pragma unroll
    for (int m = 1; m < 16; m <<= 1)
      #pragma unroll
      for (int r = 0; r < 4; ++r) mc[r] = fmaxf(mc[r], __shfl_xor(mc[r], m, 64));
    float p[4][4], ls[4];
    #pragma unroll
    for (int r = 0; r < 4; ++r) {
      float mn = fmaxf(m_run[r], mc[r]);
      float scl = expf(m_run[r] - mn);
      ls[r] = 0.f;
      #pragma unroll
      for (int n = 0; n < 4; ++n) { p[n][r] = expf(sa[n][r] - mn); ls[r] += p[n][r]; }
      m_run[r] = mn;
      l_run[r] *= scl;
      #pragma unroll
      for (int n = 0; n < 4; ++n) oacc[n][r] *= scl;
    }
    #pragma unroll
    for (int m = 1; m < 16; m <<= 1)
      #pragma unroll
      for (int r = 0; r < 4; ++r) ls[r] += __shfl_xor(ls[r], m, 64);
    #pragma unroll
    for (int r = 0; r < 4; ++r) l_run[r] += ls[r];
    #pragma unroll
    for (int n = 0; n < 4; ++n)
      #pragma unroll
      for (int r = 0; r < 4; ++r)
        Ps[wv * 16 + lkg * 4 + r][n * 16 + lrow] = __float2bfloat16(p[n][r]);
    __syncthreads();
    #pragma unroll
    for (int n = 0; n < 4; ++n)
      #pragma unroll
      for (int ks = 0; ks < 2; ++ks) {
        bv8 ap = *(bv8*)&Ps[wv * 16 + lrow][lkg * 8 + ks * 32];
        bv8 bvv = *(bv8*)&Vts[n * 16 + lrow][lkg * 8 + ks * 32];
        oacc[n] = MFMA16(ap, bvv, oacc[n]);
      }
  }
  const size_t ob = ((size_t)(b * 4096 + w * 64 + wv * 16)) * 512 + h * 64;
  #pragma unroll
  for (int n = 0; n < 4; ++n)
    #pragma unroll
    for (int r = 0; r < 4; ++r) {
      int row = lkg * 4 + r;
      olight[ob + (size_t)row * 512 + n * 16 + lrow] = __float2bfloat16(oacc[n][r] / l_run[r]);
    }
}

// ---------------- heavy attention (flash over 1025 kv incl. null) ----------------
__global__ __launch_bounds__(256)
void heavy_attn_kernel(const bf16* __restrict__ qh, const bf16* __restrict__ kvh,
                       const float* __restrict__ nkv, bf16* __restrict__ oheavy) {
  const int qt = blockIdx.x, h = blockIdx.y, b = blockIdx.z;
  const int tid = threadIdx.x;
  const int lane = tid & 63, wv = tid >> 6;
  const int lrow = lane & 15, lkg = lane >> 4;
  __shared__ bf16 Qs[64][72], Ks[64][72], Vts[64][72], Ps[64][72];
  {
    const size_t baseq = ((size_t)(b * 512 + qt * 64)) * 512 + h * 64;
    #pragma unroll
    for (int v = 0; v < 2; ++v) {
      int vec = tid + v * 256; int i = vec >> 3, dd = (vec & 7) * 8;
      *(bv8*)&Qs[i][dd] = *(const bv8*)&qh[baseq + (size_t)i * 512 + dd];
    }
  }
  fv4 oacc[4];
  float m_run[4], l_run[4];
  #pragma unroll
  for (int n = 0; n < 4; ++n) oacc[n] = (fv4){0.f, 0.f, 0.f, 0.f};
  #pragma unroll
  for (int r = 0; r < 4; ++r) { m_run[r] = -INFINITY; l_run[r] = 0.f; }
  for (int c = 0; c < 17; ++c) {
    __syncthreads();
    #pragma unroll
    for (int v = 0; v < 2; ++v) {
      int vec = tid + v * 256; int j = vec >> 3, dd = (vec & 7) * 8;
      int kvg = c * 64 + j;
      bv8 val;
      if (kvg >= 1 && kvg <= 1024) {
        val = *(const bv8*)&kvh[((size_t)(b * 1024 + kvg - 1)) * 1024 + h * 128 + dd];
      } else if (kvg == 0) {
        #pragma unroll
        for (int t = 0; t < 8; ++t) ((bf16*)&val)[t] = __float2bfloat16(nkv[h * 64 + dd + t]);
      } else {
        #pragma unroll
        for (int t = 0; t < 8; ++t) ((short*)&val)[t] = 0;
      }
      *(bv8*)&Ks[j][dd] = val;
    }
    for (int e = tid; e < 4096; e += 256) {
      int j = e >> 6, dd = e & 63;
      int kvg = c * 64 + j;
      bf16 vvv;
      if (kvg >= 1 && kvg <= 1024)
        vvv = kvh[((size_t)(b * 1024 + kvg - 1)) * 1024 + h * 128 + 64 + dd];
      else if (kvg == 0)
        vvv = __float2bfloat16(nkv[512 + h * 64 + dd]);
      else
        vvv = __float2bfloat16(0.0f);
      Vts[dd][j] = vvv;
    }
    __syncthreads();
    fv4 sa[4];
    #pragma unroll
    for (int n = 0; n < 4; ++n) {
      sa[n] = (fv4){0.f, 0.f, 0.f, 0.f};
      #pragma unroll
      for (int ks = 0; ks < 2; ++ks) {
        bv8 aq = *(bv8*)&Qs[wv * 16 + lrow][lkg * 8 + ks * 32];
        bv8 bk = *(bv8*)&Ks[n * 16 + lrow][lkg * 8 + ks * 32];
        sa[n] = MFMA16(aq, bk, sa[n]);
      }
    }
    float mc[4];
    #pragma unroll
    for (int r = 0; r < 4; ++r) {
      #pragma unroll
      for (int n = 0; n < 4; ++n) {
        sa[n][r] *= 0.125f;
        int kvg = c * 64 + n * 16 + lrow;
        if (kvg > 1024) sa[n][r] = -1e30f;
      }
      mc[r] = fmaxf(fmaxf(sa[0][r], sa[1][r]), fmaxf(sa[2][r], sa[3][r]));
    }
    #pragma unroll
    for (int m = 1; m < 16; m <<= 1)
      #pragma unroll
      for (int r = 0; r < 4; ++r) mc[r] = fmaxf(mc[r], __shfl_xor(mc[r], m, 64));
    float p[4][4], ls[4];
    #pragma unroll
    for (int r = 0; r < 4; ++r) {
      float mn = fmaxf(m_run[r], mc[r]);
      float scl = expf(m_run[r] - mn);
      ls[r] = 0.f;
      #pragma unroll
      for (int n = 0; n < 4; ++n) { p[n][r] = expf(sa[n][r] - mn); ls[r] += p[n][r]; }
      m_run[r] = mn;
      l_run[r] *= scl;
      #pragma unroll
      for (int n = 0; n < 4; ++n) oacc[n][r] *= scl;
    }
    #pragma unroll
    for (int m = 1; m < 16; m <<= 1)
      #pragma unroll
      for (int r = 0; r < 4; ++r) ls[r] += __shfl_xor(ls[r], m, 64);
    #pragma unroll
    for (int r = 0; r < 4; ++r) l_run[r] += ls[r];
    #pragma unroll
    for (int n = 0; n < 4; ++n)
      #pragma unroll
      for (int r = 0; r < 4; ++r)
        Ps[wv * 16 + lkg * 4 + r][n * 16 + lrow] = __float2bfloat16(p[n][r]);
    __syncthreads();
    #pragma unroll
    for (int n = 0; n < 4; ++n)
      #pragma unroll
      for (int ks = 0; ks < 2; ++ks) {
        bv8 ap = *(bv8*)&Ps[wv * 16 + lrow][lkg * 8 + ks * 32];
        bv8 bvv = *(bv8*)&Vts[n * 16 + lrow][lkg * 8 + ks * 32];
        oacc[n] = MFMA16(ap, bvv, oacc[n]);
      }
  }
  const size_t ob = ((size_t)(b * 512 + qt * 64 + wv * 16)) * 512 + h * 64;
  #pragma unroll
  for (int n = 0; n < 4; ++n)
    #pragma unroll
    for (int r = 0; r < 4; ++r) {
      int row = lkg * 4 + r;
      oheavy[ob + (size_t)row * 512 + n * 16 + lrow] = __float2bfloat16(oacc[n][r] / l_run[r]);
    }
}

// ---------------- launcher ----------------
extern "C" void kernel_launch(void* const* d_in, const int* in_sizes, int n_in,
                              void* d_out, int out_size, void* d_ws, size_t ws_size,
                              hipStream_t stream) {
  (void)in_sizes; (void)n_in; (void)out_size; (void)ws_size;
  const float* x     = (const float*)d_in[0];
  const float* ln_w  = (const float*)d_in[1];
  const float* ln_b  = (const float*)d_in[2];
  const float* Wqkv  = (const float*)d_in[3];
  const float* Woutl = (const float*)d_in[4];
  const float* rtq   = (const float*)d_in[5];
  const float* rtkv  = (const float*)d_in[6];
  const float* gamma = (const float*)d_in[7];
  const float* Wq    = (const float*)d_in[8];
  const float* Wkv   = (const float*)d_in[9];
  const float* Wouth = (const float*)d_in[10];
  const float* nkv   = (const float*)d_in[11];
  const float* nq    = (const float*)d_in[12];
  float* out = (float*)d_out;

  char* ws = (char*)d_ws;
  size_t off = 0;
  auto alloc = [&](size_t bytes) -> void* {
    void* p = ws + off;
    off = (off + bytes + 255) & ~(size_t)255;
    return p;
  };
  bf16* ln_bf    = (bf16*)alloc(16384ull * 1024 * 2);
  bf16* qkv_bf   = (bf16*)alloc(16384ull * 1536 * 2);
  bf16* ol_bf    = (bf16*)alloc(16384ull * 512 * 2);
  bf16* Wqkv_bf  = (bf16*)alloc(1536ull * 1024 * 2);
  bf16* Woutl_bf = (bf16*)alloc(1024ull * 512 * 2);
  bf16* Wq_bf    = (bf16*)alloc(512ull * 1024 * 2);
  bf16* Wkv_bf   = (bf16*)alloc(1024ull * 1024 * 2);
  bf16* Wouth_bf = (bf16*)alloc(1024ull * 512 * 2);
  double* s_d    = (double*)alloc(32768ull * 8);
  int* iq        = (int*)alloc(2048ull * 4);
  int* ikv       = (int*)alloc(4096ull * 4);
  int* posq      = (int*)alloc(16384ull * 4);
  bf16* xq_bf    = (bf16*)alloc(2048ull * 1024 * 2);
  bf16* xkv_bf   = (bf16*)alloc(4096ull * 1024 * 2);
  bf16* qh_bf    = (bf16*)alloc(2048ull * 512 * 2);
  bf16* kvh_bf   = (bf16*)alloc(4096ull * 1024 * 2);
  bf16* oh_bf    = (bf16*)alloc(2048ull * 512 * 2);
  float* heavy_f = (float*)alloc(2048ull * 1024 * 4);

  // weight casts
  cast_f2b_kernel<<<512, 256, 0, stream>>>(Wqkv,  Wqkv_bf,  1536 * 1024);
  cast_f2b_kernel<<<512, 256, 0, stream>>>(Woutl, Woutl_bf, 1024 * 512);
  cast_f2b_kernel<<<512, 256, 0, stream>>>(Wq,    Wq_bf,    512 * 1024);
  cast_f2b_kernel<<<512, 256, 0, stream>>>(Wkv,   Wkv_bf,   1024 * 1024);
  cast_f2b_kernel<<<512, 256, 0, stream>>>(Wouth, Wouth_bf, 1024 * 512);

  // fused LN + routing dots
  ln_sdot_kernel<<<16384, 256, 0, stream>>>(x, ln_w, ln_b, rtq, rtkv, ln_bf, s_d);

  // routing iterations + selection
  hipMemsetAsync(posq, 0xFF, 16384 * 4, stream);
  route_sel_kernel<<<8, 1024, 0, stream>>>(s_d, iq, ikv, posq);

  // light path
  gemm_bt<0><<<dim3(12, 128), 256, 0, stream>>>(ln_bf, Wqkv_bf, qkv_bf, 16384, 1536, 1024,
                                                nullptr, nullptr, nullptr);
  local_attn_kernel<<<dim3(64, 8, 4), 256, 0, stream>>>(qkv_bf, ol_bf);

  // heavy path
  gather_rms_kernel<<<6144, 256, 0, stream>>>(x, gamma, iq, ikv, xq_bf, xkv_bf);
  gemm_bt<0><<<dim3(4, 16), 256, 0, stream>>>(xq_bf, Wq_bf, qh_bf, 2048, 512, 1024,
                                              nullptr, nullptr, nullptr);
  gemm_bt<0><<<dim3(8, 32), 256, 0, stream>>>(xkv_bf, Wkv_bf, kvh_bf, 4096, 1024, 1024,
                                              nullptr, nullptr, nullptr);
  heavy_attn_kernel<<<dim3(8, 8, 4), 256, 0, stream>>>(qh_bf, kvh_bf, nkv, oh_bf);
  gemm_bt<1><<<dim3(8, 16), 256, 0, stream>>>(oh_bf, Wouth_bf, heavy_f, 2048, 1024, 512,
                                              nullptr, nullptr, nullptr);

  // light output GEMM + fused combine (heavy scatter / null_q) -> d_out
  gemm_bt<2><<<dim3(8, 128), 256, 0, stream>>>(ol_bf, Woutl_bf, out, 16384, 1024, 512,
                                               posq, heavy_f, nq);
}

// Round 3
// 415.178 us; speedup vs baseline: 1.4856x; 1.2076x over previous
//
#include <hip/hip_runtime.h>
#include <hip/hip_bf16.h>

typedef __attribute__((ext_vector_type(8))) short bv8;
typedef __attribute__((ext_vector_type(4))) float fv4;
typedef __hip_bfloat16 bf16;

#define MFMA16(a,b,c) __builtin_amdgcn_mfma_f32_16x16x32_bf16((a),(b),(c),0,0,0)
#define GLOAD_LDS(gp, lp) __builtin_amdgcn_global_load_lds( \
    (const __attribute__((address_space(1))) void*)(gp), \
    (__attribute__((address_space(3))) void*)(lp), 16, 0, 0)

// ---------------- block reduce helpers ----------------
template<int NW>
__device__ __forceinline__ float blockReduceSumF(float v) {
  #pragma unroll
  for (int m = 1; m < 64; m <<= 1) v += __shfl_xor(v, m, 64);
  __shared__ float sm[NW];
  if ((threadIdx.x & 63) == 0) sm[threadIdx.x >> 6] = v;
  __syncthreads();
  float t = 0.f;
  #pragma unroll
  for (int i = 0; i < NW; ++i) t += sm[i];
  __syncthreads();
  return t;
}

template<int NW>
__device__ __forceinline__ double blockReduceSumD(double v) {
  #pragma unroll
  for (int m = 1; m < 64; m <<= 1) v += __shfl_xor(v, m, 64);
  __shared__ double sm[NW];
  if ((threadIdx.x & 63) == 0) sm[threadIdx.x >> 6] = v;
  __syncthreads();
  double t = 0.0;
  #pragma unroll
  for (int i = 0; i < NW; ++i) t += sm[i];
  __syncthreads();
  return t;
}

template<int NW>
__device__ __forceinline__ double blockReduceMaxD(double v) {
  #pragma unroll
  for (int m = 1; m < 64; m <<= 1) v = fmax(v, __shfl_xor(v, m, 64));
  __shared__ double sm[NW];
  if ((threadIdx.x & 63) == 0) sm[threadIdx.x >> 6] = v;
  __syncthreads();
  double t = sm[0];
  #pragma unroll
  for (int i = 1; i < NW; ++i) t = fmax(t, sm[i]);
  __syncthreads();
  return t;
}

// ---------------- fused weight cast (5 segments, 8 elems/thread) ----------------
__global__ __launch_bounds__(256)
void cast5_kernel(const float* __restrict__ a0, const float* __restrict__ a1,
                  const float* __restrict__ a2, const float* __restrict__ a3,
                  const float* __restrict__ a4,
                  bf16* __restrict__ b0, bf16* __restrict__ b1, bf16* __restrict__ b2,
                  bf16* __restrict__ b3, bf16* __restrict__ b4) {
  size_t g = ((size_t)blockIdx.x * 256 + threadIdx.x) * 8;
  const float* src; bf16* dst; size_t off;
  if (g < 1572864)      { src = a0; dst = b0; off = g; }
  else if (g < 2097152) { src = a1; dst = b1; off = g - 1572864; }
  else if (g < 2621440) { src = a2; dst = b2; off = g - 2097152; }
  else if (g < 3670016) { src = a3; dst = b3; off = g - 2621440; }
  else                  { src = a4; dst = b4; off = g - 3670016; }
  float4 v0 = *(const float4*)(src + off);
  float4 v1 = *(const float4*)(src + off + 4);
  bv8 o;
  ((bf16*)&o)[0] = __float2bfloat16(v0.x); ((bf16*)&o)[1] = __float2bfloat16(v0.y);
  ((bf16*)&o)[2] = __float2bfloat16(v0.z); ((bf16*)&o)[3] = __float2bfloat16(v0.w);
  ((bf16*)&o)[4] = __float2bfloat16(v1.x); ((bf16*)&o)[5] = __float2bfloat16(v1.y);
  ((bf16*)&o)[6] = __float2bfloat16(v1.z); ((bf16*)&o)[7] = __float2bfloat16(v1.w);
  *(bv8*)(dst + off) = o;
}

// Fused LayerNorm (-> bf16) + routing dot products (fp64)
__global__ __launch_bounds__(256)
void ln_sdot_kernel(const float* __restrict__ x, const float* __restrict__ w,
                    const float* __restrict__ bb, const float* __restrict__ rtq,
                    const float* __restrict__ rtkv, bf16* __restrict__ out,
                    double* __restrict__ s) {
  const int r = blockIdx.x;
  const float* xr = x + (size_t)r * 1024;
  float v4[4]; float ssum = 0.f;
  double dq = 0.0, dk = 0.0;
  #pragma unroll
  for (int i = 0; i < 4; ++i) {
    int d = threadIdx.x + i * 256;
    float v = xr[d];
    v4[i] = v; ssum += v;
    dq += (double)v * (double)rtq[d];
    dk += (double)v * (double)rtkv[d];
  }
  ssum = blockReduceSumF<4>(ssum);
  const float mean = ssum * (1.0f / 1024.0f);
  float vs = 0.f;
  #pragma unroll
  for (int i = 0; i < 4; ++i) { float d = v4[i] - mean; vs += d * d; }
  vs = blockReduceSumF<4>(vs);
  const float rstd = 1.0f / sqrtf(vs * (1.0f / 1024.0f) + 1e-5f);
  dq = blockReduceSumD<4>(dq);
  dk = blockReduceSumD<4>(dk);
  if (threadIdx.x == 0) { s[r] = dq; s[16384 + r] = dk; }
  bf16* orow = out + (size_t)r * 1024;
  #pragma unroll
  for (int i = 0; i < 4; ++i) {
    int d = threadIdx.x + i * 256;
    orow[d] = __float2bfloat16((v4[i] - mean) * rstd * w[d] + bb[d]);
  }
}

// Fused routing: 50 fixed-point iterations (closed form via precomputed exp)
// + threshold selection (prefix scan fast path; bitonic fallback).
__global__ __launch_bounds__(1024)
void route_sel_kernel(const double* __restrict__ s_all, int* __restrict__ iq,
                      int* __restrict__ ikv, int* __restrict__ posq) {
  const int route = blockIdx.x >> 2, b = blockIdx.x & 3;
  const double* s = s_all + route * 16384 + b * 4096;
  const double logk = (route == 0) ? log(576.0) : log(1152.0);
  const int KSEL = (route == 0) ? 512 : 1024;
  const int tid = threadIdx.x;
  const int lane = tid & 63, wid = tid >> 6;
  double sv[4], ev[4];
  #pragma unroll
  for (int i = 0; i < 4; ++i) sv[i] = s[tid * 4 + i];
  double mx = fmax(fmax(sv[0], sv[1]), fmax(sv[2], sv[3]));
  mx = blockReduceMaxD<16>(mx);
  #pragma unroll
  for (int i = 0; i < 4; ++i) ev[i] = exp(sv[i] - mx);
  __shared__ double red[32];
  __shared__ double a_sh;
  double a = logk - log(4096.0);   // iteration 1 (bb = -s  =>  logsumexp = log(4096))
  for (int it = 1; it < 50; ++it) {
    const double T = -a;
    double cnt = 0.0, us = 0.0;
    #pragma unroll
    for (int i = 0; i < 4; ++i) {
      if (sv[i] >= T) cnt += 1.0; else us += ev[i];
    }
    #pragma unroll
    for (int m = 1; m < 64; m <<= 1) { cnt += __shfl_xor(cnt, m, 64); us += __shfl_xor(us, m, 64); }
    if (lane == 0) { red[wid] = cnt; red[16 + wid] = us; }
    __syncthreads();
    if (tid == 0) {
      double tc = 0.0, tu = 0.0;
      #pragma unroll
      for (int i = 0; i < 16; ++i) { tc += red[i]; tu += red[16 + i]; }
      double se = tc * exp(T - mx) + tu;
      a_sh = logk - (mx + log(se));
    }
    __syncthreads();
    a = a_sh;
  }
  // final scores (fp32, matching reference semantics incl. rounding-to-1.0f ties)
  float scf[4]; int m4 = 0;
  #pragma unroll
  for (int i = 0; i < 4; ++i) {
    double v = sv[i] + a;
    scf[i] = (float)exp(fmin(v, 0.0));
    m4 += (scf[i] == 1.0f) ? 1 : 0;
  }
  __shared__ int scn[1024];
  scn[tid] = m4;
  __syncthreads();
  for (int off = 1; off < 1024; off <<= 1) {
    int v = (tid >= off) ? scn[tid - off] : 0;
    __syncthreads();
    scn[tid] += v;
    __syncthreads();
  }
  const int total = scn[1023];
  const int excl = scn[tid] - m4;
  if (total >= KSEL) {
    // fast path: top-K = first K saturated (score==1.0f) in ascending index order
    int rk = excl;
    #pragma unroll
    for (int i = 0; i < 4; ++i) {
      if (scf[i] == 1.0f) {
        if (rk < KSEL) {
          int idx = tid * 4 + i;
          if (route == 0) { iq[b * 512 + rk] = idx; posq[b * 4096 + idx] = rk; }
          else            { ikv[b * 1024 + rk] = idx; }
        }
        rk++;
      }
    }
  } else {
    // fallback: full bitonic sort (score desc, index asc) — replicates R1 topk
    __shared__ unsigned long long keys[4096];
    #pragma unroll
    for (int i = 0; i < 4; ++i) {
      unsigned bits = __float_as_uint(scf[i]);   // scores in [0,1] -> bits monotone
      keys[tid * 4 + i] = ((unsigned long long)(~bits) << 32) | (unsigned long long)(tid * 4 + i);
    }
    for (int k = 2; k <= 4096; k <<= 1) {
      for (int j = k >> 1; j > 0; j >>= 1) {
        __syncthreads();
        for (int t = tid; t < 2048; t += 1024) {
          int i2 = ((t & ~(j - 1)) << 1) | (t & (j - 1));
          int ip = i2 + j;
          unsigned long long av = keys[i2], bvv = keys[ip];
          bool up = ((i2 & k) == 0);
          if (up ? (av > bvv) : (av < bvv)) { keys[i2] = bvv; keys[ip] = av; }
        }
      }
    }
    __syncthreads();
    for (int j2 = tid; j2 < KSEL; j2 += 1024) {
      int idx = (int)(keys[j2] & 0xFFFFFFFFull);
      if (route == 0) { iq[b * 512 + j2] = idx; posq[b * 4096 + idx] = j2; }
      else            { ikv[b * 1024 + j2] = idx; }
    }
  }
}

// gather selected tokens + RMS norm -> bf16
__global__ __launch_bounds__(256)
void gather_rms_kernel(const float* __restrict__ x, const float* __restrict__ gamma,
                       const int* __restrict__ iq, const int* __restrict__ ikv,
                       bf16* __restrict__ xq, bf16* __restrict__ xkv) {
  const int bid = blockIdx.x;
  const float* src; bf16* dst;
  if (bid < 2048) {
    int b = bid >> 9, j = bid & 511;
    int tok = iq[b * 512 + j];
    src = x + ((size_t)(b * 4096 + tok)) * 1024;
    dst = xq + (size_t)bid * 1024;
  } else {
    int id = bid - 2048;
    int b = id >> 10, j = id & 1023;
    int tok = ikv[b * 1024 + j];
    src = x + ((size_t)(b * 4096 + tok)) * 1024;
    dst = xkv + (size_t)id * 1024;
  }
  float v4[4]; float ss = 0.f;
  #pragma unroll
  for (int i = 0; i < 4; ++i) { v4[i] = src[threadIdx.x + i * 256]; ss += v4[i] * v4[i]; }
  ss = blockReduceSumF<4>(ss);
  const float nrm = fmaxf(sqrtf(ss), 1e-12f);
  const float scl = 32.0f / nrm;
  #pragma unroll
  for (int i = 0; i < 4; ++i) {
    int d = threadIdx.x + i * 256;
    dst[d] = __float2bfloat16(v4[i] * scl * gamma[d]);
  }
}

// ---------------- GEMM: C(MxN) = A(MxK) * B(NxK)^T, bf16 in, fp32 acc ----------------
// m97-style: linear [128][32] LDS tiles staged via global_load_lds width 16.
// EPI: 0 = bf16 store, 1 = f32 store, 2 = f32 store + combine (light + heavy/null_q)
template<int EPI>
__global__ __launch_bounds__(256)
void gemm_bt(const bf16* __restrict__ A, const bf16* __restrict__ B, void* __restrict__ Cout,
             int M, int N, int K,
             const int* __restrict__ posq, const float* __restrict__ heavy,
             const float* __restrict__ nullq) {
  __shared__ alignas(16) bf16 As[128 * 32];
  __shared__ alignas(16) bf16 Bs[128 * 32];
  const int tid = threadIdx.x;
  const int lane = tid & 63, w = tid >> 6;
  const int wr = w >> 1, wc = w & 1;
  const int lrow = lane & 15, lk = (lane >> 4) * 8;
  const int row0 = blockIdx.y * 128, col0 = blockIdx.x * 128;
  fv4 acc[4][4];
  #pragma unroll
  for (int m = 0; m < 4; ++m)
    #pragma unroll
    for (int n = 0; n < 4; ++n) acc[m][n] = (fv4){0.f, 0.f, 0.f, 0.f};
  // per-lane staging source mapping (LDS linear: byte off = r*64 + c*16)
  const int ob0 = w * 2048;
  for (int k0 = 0; k0 < K; k0 += 32) {
    #pragma unroll
    for (int t = 0; t < 2; ++t) {
      int ob = ob0 + t * 1024;
      int ofl = ob + lane * 16;
      int r = ofl >> 6, c8 = ((ofl >> 4) & 3) * 8;
      GLOAD_LDS(A + (size_t)(row0 + r) * K + k0 + c8, (char*)As + ob);
      GLOAD_LDS(B + (size_t)(col0 + r) * K + k0 + c8, (char*)Bs + ob);
    }
    __syncthreads();   // drains vmcnt -> LDS tiles ready
    bv8 af[4], bfr[4];
    #pragma unroll
    for (int m = 0; m < 4; ++m) af[m] = *(bv8*)&As[(wr * 64 + m * 16 + lrow) * 32 + lk];
    #pragma unroll
    for (int n = 0; n < 4; ++n) bfr[n] = *(bv8*)&Bs[(wc * 64 + n * 16 + lrow) * 32 + lk];
    #pragma unroll
    for (int m = 0; m < 4; ++m)
      #pragma unroll
      for (int n = 0; n < 4; ++n)
        acc[m][n] = MFMA16(af[m], bfr[n], acc[m][n]);
    __syncthreads();
  }
  #pragma unroll
  for (int m = 0; m < 4; ++m) {
    int gr0 = row0 + wr * 64 + m * 16 + (lane >> 4) * 4;
    #pragma unroll
    for (int n = 0; n < 4; ++n) {
      int gc = col0 + wc * 64 + n * 16 + lrow;
      #pragma unroll
      for (int r = 0; r < 4; ++r) {
        int grow = gr0 + r;
        float vv = acc[m][n][r];
        if (EPI == 0) {
          ((bf16*)Cout)[(size_t)grow * N + gc] = __float2bfloat16(vv);
        } else if (EPI == 1) {
          ((float*)Cout)[(size_t)grow * N + gc] = vv;
        } else {
          int p = posq[grow];
          float add = (p >= 0) ? heavy[((size_t)((grow >> 12) * 512 + p)) * 1024 + gc]
                               : nullq[gc];
          ((float*)Cout)[(size_t)grow * N + gc] = vv + add;
        }
      }
    }
  }
}

// ---------------- local windowed attention (flash over 3 windows) ----------------
__global__ __launch_bounds__(256)
void local_attn_kernel(const bf16* __restrict__ qkv, bf16* __restrict__ olight) {
  const int w = blockIdx.x, h = blockIdx.y, b = blockIdx.z;
  const int tid = threadIdx.x;
  const int lane = tid & 63, wv = tid >> 6;
  const int lrow = lane & 15, lkg = lane >> 4;
  __shared__ bf16 Qs[64][72], Ks[64][72], Vts[64][72], Ps[64][72];
  {
    const size_t baseq = ((size_t)(b * 4096 + w * 64)) * 1536 + h * 64;
    #pragma unroll
    for (int v = 0; v < 2; ++v) {
      int vec = tid + v * 256; int i = vec >> 3, dd = (vec & 7) * 8;
      *(bv8*)&Qs[i][dd] = *(const bv8*)&qkv[baseq + (size_t)i * 1536 + dd];
    }
  }
  fv4 oacc[4];
  float m_run[4], l_run[4];
  #pragma unroll
  for (int n = 0; n < 4; ++n) oacc[n] = (fv4){0.f, 0.f, 0.f, 0.f};
  #pragma unroll
  for (int r = 0; r < 4; ++r) { m_run[r] = -INFINITY; l_run[r] = 0.f; }
  for (int c = 0; c < 3; ++c) {
    int sw = w - 1 + c;
    if (sw < 0 || sw >= 64) continue;           // uniform across block
    __syncthreads();
    const size_t bkv = ((size_t)(b * 4096 + sw * 64)) * 1536 + h * 64;
    #pragma unroll
    for (int v = 0; v < 2; ++v) {
      int vec = tid + v * 256; int i = vec >> 3, dd = (vec & 7) * 8;
      *(bv8*)&Ks[i][dd] = *(const bv8*)&qkv[bkv + 512 + (size_t)i * 1536 + dd];
    }
    for (int e = tid; e < 4096; e += 256) {
      int j = e >> 6, dd = e & 63;
      Vts[dd][j] = qkv[bkv + 1024 + (size_t)j * 1536 + dd];
    }
    __syncthreads();
    fv4 sa[4];
    #pragma unroll
    for (int n = 0; n < 4; ++n) {
      sa[n] = (fv4){0.f, 0.f, 0.f, 0.f};
      #pragma unroll
      for (int ks = 0; ks < 2; ++ks) {
        bv8 aq = *(bv8*)&Qs[wv * 16 + lrow][lkg * 8 + ks * 32];
        bv8 bk = *(bv8*)&Ks[n * 16 + lrow][lkg * 8 + ks * 32];
        sa[n] = MFMA16(aq, bk, sa[n]);
      }
    }
    float mc[4];
    #pragma unroll
    for (int r = 0; r < 4; ++r) {
      #pragma unroll
      for (int n = 0; n < 4; ++n) sa[n][r] *= 0.125f;
      mc[r] = fmaxf(fmaxf(sa[0][r], sa[1][r]), fmaxf(sa[2][r], sa[3][r]));
    }
    #pragma unroll
    for (int m = 1; m < 16; m <<= 1)
      #pragma unroll
      for (int r = 0; r < 4; ++r) mc[r] = fmaxf(mc[r], __shfl_xor(mc[r], m, 64));
    float p[4][4], ls[4];
    #pragma unroll
    for (int r = 0; r < 4; ++r) {
      float mn = fmaxf(m_run[r], mc[r]);
      float scl = expf(m_run[r] - mn);
      ls[r] = 0.f;
      #pragma unroll
      for (int n = 0; n < 4; ++n) { p[n][r] = expf(sa[n][r] - mn); ls[r] += p[n][r]; }
      m_run[r] = mn;
      l_run[r] *= scl;
      #pragma unroll
      for (int n = 0; n < 4; ++n) oacc[n][r] *= scl;
    }
    #pragma unroll
    for (int m = 1; m < 16; m <<= 1)
      #pragma unroll
      for (int r = 0; r < 4; ++r) ls[r] += __shfl_xor(ls[r], m, 64);
    #pragma unroll
    for (int r = 0; r < 4; ++r) l_run[r] += ls[r];
    #pragma unroll
    for (int n = 0; n < 4; ++n)
      #pragma unroll
      for (int r = 0; r < 4; ++r)
        Ps[wv * 16 + lkg * 4 + r][n * 16 + lrow] = __float2bfloat16(p[n][r]);
    __syncthreads();
    #pragma unroll
    for (int n = 0; n < 4; ++n)
      #pragma unroll
      for (int ks = 0; ks < 2; ++ks) {
        bv8 ap = *(bv8*)&Ps[wv * 16 + lrow][lkg * 8 + ks * 32];
        bv8 bvv = *(bv8*)&Vts[n * 16 + lrow][lkg * 8 + ks * 32];
        oacc[n] = MFMA16(ap, bvv, oacc[n]);
      }
  }
  const size_t ob = ((size_t)(b * 4096 + w * 64 + wv * 16)) * 512 + h * 64;
  #pragma unroll
  for (int n = 0; n < 4; ++n)
    #pragma unroll
    for (int r = 0; r < 4; ++r) {
      int row = lkg * 4 + r;
      olight[ob + (size_t)row * 512 + n * 16 + lrow] = __float2bfloat16(oacc[n][r] / l_run[r]);
    }
}

// ---------------- heavy attention: split-K flash partials ----------------
// blockIdx: x=qt(8), y=h(8), z=b*4+split
// split 0: tiles 0..4 (incl null at kvg=0); split s: tiles s*4+1 .. s*4+4
__global__ __launch_bounds__(256)
void heavy_attn_split_kernel(const bf16* __restrict__ qh, const bf16* __restrict__ kvh,
                             const float* __restrict__ nkv, float* __restrict__ o_part,
                             float* __restrict__ ml_part) {
  const int qt = blockIdx.x, h = blockIdx.y;
  const int b = blockIdx.z >> 2, s = blockIdx.z & 3;
  const int tid = threadIdx.x;
  const int lane = tid & 63, wv = tid >> 6;
  const int lrow = lane & 15, lkg = lane >> 4;
  __shared__ bf16 Qs[64][72], Ks[64][72], Vts[64][72], Ps[64][72];
  {
    const size_t baseq = ((size_t)(b * 512 + qt * 64)) * 512 + h * 64;
    #pragma unroll
    for (int v = 0; v < 2; ++v) {
      int vec = tid + v * 256; int i = vec >> 3, dd = (vec & 7) * 8;
      *(bv8*)&Qs[i][dd] = *(const bv8*)&qh[baseq + (size_t)i * 512 + dd];
    }
  }
  fv4 oacc[4];
  float m_run[4], l_run[4];
  #pragma unroll
  for (int n = 0; n < 4; ++n) oacc[n] = (fv4){0.f, 0.f, 0.f, 0.f};
  #pragma unroll
  for (int r = 0; r < 4; ++r) { m_run[r] = -INFINITY; l_run[r] = 0.f; }
  const int cs = (s == 0) ? 0 : (s * 4 + 1);
  const int ce = s * 4 + 5;
  for (int c = cs; c < ce; ++c) {
    __syncthreads();
    #pragma unroll
    for (int v = 0; v < 2; ++v) {
      int vec = tid + v * 256; int j = vec >> 3, dd = (vec & 7) * 8;
      int kvg = c * 64 + j;
      bv8 val;
      if (kvg >= 1 && kvg <= 1024) {
        val = *(const bv8*)&kvh[((size_t)(b * 1024 + kvg - 1)) * 1024 + h * 128 + dd];
      } else if (kvg == 0) {
        #pragma unroll
        for (int t = 0; t < 8; ++t) ((bf16*)&val)[t] = __float2bfloat16(nkv[h * 64 + dd + t]);
      } else {
        #pragma unroll
        for (int t = 0; t < 8; ++t) ((short*)&val)[t] = 0;
      }
      *(bv8*)&Ks[j][dd] = val;
    }
    for (int e = tid; e < 4096; e += 256) {
      int j = e >> 6, dd = e & 63;
      int kvg = c * 64 + j;
      bf16 vvv;
      if (kvg >= 1 && kvg <= 1024)
        vvv = kvh[((size_t)(b * 1024 + kvg - 1)) * 1024 + h * 128 + 64 + dd];
      else if (kvg == 0)
        vvv = __float2bfloat16(nkv[512 + h * 64 + dd]);
      else
        vvv = __float2bfloat16(0.0f);
      Vts[dd][j] = vvv;
    }
    __syncthreads();
    fv4 sa[4];
    #pragma unroll
    for (int n = 0; n < 4; ++n) {
      sa[n] = (fv4){0.f, 0.f, 0.f, 0.f};
      #pragma unroll
      for (int ks = 0; ks < 2; ++ks) {
        bv8 aq = *(bv8*)&Qs[wv * 16 + lrow][lkg * 8 + ks * 32];
        bv8 bk = *(bv8*)&Ks[n * 16 + lrow][lkg * 8 + ks * 32];
        sa[n] = MFMA16(aq, bk, sa[n]);
      }
    }
    float mc[4];
    #pragma unroll
    for (int r = 0; r < 4; ++r) {
      #pragma unroll
      for (int n = 0; n < 4; ++n) {
        sa[n][r] *= 0.125f;
        int kvg = c * 64 + n * 16 + lrow;
        if (kvg > 1024) sa[n][r] = -1e30f;
      }
      mc[r] = fmaxf(fmaxf(sa[0][r], sa[1][r]), fmaxf(sa[2][r], sa[3][r]));
    }
    #pragma unroll
    for (int m = 1; m < 16; m <<= 1)
      #pragma unroll
      for (int r = 0; r < 4; ++r) mc[r] = fmaxf(mc[r], __shfl_xor(mc[r], m, 64));
    float p[4][4], ls[4];
    #pragma unroll
    for (int r = 0; r < 4; ++r) {
      float mn = fmaxf(m_run[r], mc[r]);
      float scl = expf(m_run[r] - mn);
      ls[r] = 0.f;
      #pragma unroll
      for (int n = 0; n < 4; ++n) { p[n][r] = expf(sa[n][r] - mn); ls[r] += p[n][r]; }
      m_run[r] = mn;
      l_run[r] *= scl;
      #pragma unroll
      for (int n = 0; n < 4; ++n) oacc[n][r] *= scl;
    }
    #pragma unroll
    for (int m = 1; m < 16; m <<= 1)
      #pragma unroll
      for (int r = 0; r < 4; ++r) ls[r] += __shfl_xor(ls[r], m, 64);
    #pragma unroll
    for (int r = 0; r < 4; ++r) l_run[r] += ls[r];
    #pragma unroll
    for (int n = 0; n < 4; ++n)
      #pragma unroll
      for (int r = 0; r < 4; ++r)
        Ps[wv * 16 + lkg * 4 + r][n * 16 + lrow] = __float2bfloat16(p[n][r]);
    __syncthreads();
    #pragma unroll
    for (int n = 0; n < 4; ++n)
      #pragma unroll
      for (int ks = 0; ks < 2; ++ks) {
        bv8 ap = *(bv8*)&Ps[wv * 16 + lrow][lkg * 8 + ks * 32];
        bv8 bvv = *(bv8*)&Vts[n * 16 + lrow][lkg * 8 + ks * 32];
        oacc[n] = MFMA16(ap, bvv, oacc[n]);
      }
  }
  // store partials (no normalization)
  const int idx = (((s * 4 + b) * 8 + h) * 8 + qt);
  float* ob = o_part + (size_t)idx * 4096;
  #pragma unroll
  for (int n = 0; n < 4; ++n)
    #pragma unroll
    for (int r = 0; r < 4; ++r) {
      int row = wv * 16 + lkg * 4 + r;
      ob[row * 64 + n * 16 + lrow] = oacc[n][r];
    }
  if (lrow == 0) {
    #pragma unroll
    for (int r = 0; r < 4; ++r) {
      int row = wv * 16 + lkg * 4 + r;
      ml_part[idx * 128 + row] = m_run[r];
      ml_part[idx * 128 + 64 + row] = l_run[r];
    }
  }
}

// combine split partials -> bf16 heavy attention output
__global__ __launch_bounds__(256)
void heavy_combine_kernel(const float* __restrict__ o_part, const float* __restrict__ ml_part,
                          bf16* __restrict__ oh) {
  const int qt = blockIdx.x, h = blockIdx.y, b = blockIdx.z;
  const int tid = threadIdx.x;
  const int row = tid >> 2, c0 = (tid & 3) * 16;
  int idx[4]; float m[4], l[4];
  #pragma unroll
  for (int s = 0; s < 4; ++s) {
    idx[s] = (((s * 4 + b) * 8 + h) * 8 + qt);
    m[s] = ml_part[idx[s] * 128 + row];
    l[s] = ml_part[idx[s] * 128 + 64 + row];
  }
  const float mstar = fmaxf(fmaxf(m[0], m[1]), fmaxf(m[2], m[3]));
  float wsum = 0.f, w[4];
  #pragma unroll
  for (int s = 0; s < 4; ++s) { w[s] = expf(m[s] - mstar); wsum += w[s] * l[s]; }
  const float inv = 1.0f / wsum;
  float o[16];
  #pragma unroll
  for (int i = 0; i < 16; ++i) o[i] = 0.f;
  #pragma unroll
  for (int s = 0; s < 4; ++s) {
    const fv4* op = (const fv4*)(o_part + (size_t)idx[s] * 4096 + row * 64 + c0);
    #pragma unroll
    for (int k = 0; k < 4; ++k) {
      fv4 v = op[k];
      #pragma unroll
      for (int j = 0; j < 4; ++j) o[k * 4 + j] += w[s] * v[j];
    }
  }
  const size_t ob = ((size_t)(b * 512 + qt * 64 + row)) * 512 + h * 64 + c0;
  bv8 pk[2];
  #pragma unroll
  for (int i = 0; i < 16; ++i) ((bf16*)pk)[i] = __float2bfloat16(o[i] * inv);
  *(bv8*)&oh[ob] = pk[0];
  *(bv8*)&oh[ob + 8] = pk[1];
}

// ---------------- launcher ----------------
extern "C" void kernel_launch(void* const* d_in, const int* in_sizes, int n_in,
                              void* d_out, int out_size, void* d_ws, size_t ws_size,
                              hipStream_t stream) {
  (void)in_sizes; (void)n_in; (void)out_size; (void)ws_size;
  const float* x     = (const float*)d_in[0];
  const float* ln_w  = (const float*)d_in[1];
  const float* ln_b  = (const float*)d_in[2];
  const float* Wqkv  = (const float*)d_in[3];
  const float* Woutl = (const float*)d_in[4];
  const float* rtq   = (const float*)d_in[5];
  const float* rtkv  = (const float*)d_in[6];
  const float* gamma = (const float*)d_in[7];
  const float* Wq    = (const float*)d_in[8];
  const float* Wkv   = (const float*)d_in[9];
  const float* Wouth = (const float*)d_in[10];
  const float* nkv   = (const float*)d_in[11];
  const float* nq    = (const float*)d_in[12];
  float* out = (float*)d_out;

  char* ws = (char*)d_ws;
  size_t off = 0;
  auto alloc = [&](size_t bytes) -> void* {
    void* p = ws + off;
    off = (off + bytes + 255) & ~(size_t)255;
    return p;
  };
  bf16* ln_bf    = (bf16*)alloc(16384ull * 1024 * 2);
  bf16* qkv_bf   = (bf16*)alloc(16384ull * 1536 * 2);
  bf16* ol_bf    = (bf16*)alloc(16384ull * 512 * 2);
  bf16* Wqkv_bf  = (bf16*)alloc(1536ull * 1024 * 2);
  bf16* Woutl_bf = (bf16*)alloc(1024ull * 512 * 2);
  bf16* Wq_bf    = (bf16*)alloc(512ull * 1024 * 2);
  bf16* Wkv_bf   = (bf16*)alloc(1024ull * 1024 * 2);
  bf16* Wouth_bf = (bf16*)alloc(1024ull * 512 * 2);
  double* s_d    = (double*)alloc(32768ull * 8);
  int* iq        = (int*)alloc(2048ull * 4);
  int* ikv       = (int*)alloc(4096ull * 4);
  int* posq      = (int*)alloc(16384ull * 4);
  bf16* xq_bf    = (bf16*)alloc(2048ull * 1024 * 2);
  bf16* xkv_bf   = (bf16*)alloc(4096ull * 1024 * 2);
  bf16* qh_bf    = (bf16*)alloc(2048ull * 512 * 2);
  bf16* kvh_bf   = (bf16*)alloc(4096ull * 1024 * 2);
  bf16* oh_bf    = (bf16*)alloc(2048ull * 512 * 2);
  float* heavy_f = (float*)alloc(2048ull * 1024 * 4);
  float* o_part  = (float*)alloc(4096ull * 4096 * 4);   // 4 splits x 1024 tiles x 64x64 f32
  float* ml_part = (float*)alloc(4096ull * 128 * 4);

  // fused weight casts (4M elements total)
  cast5_kernel<<<2048, 256, 0, stream>>>(Wqkv, Woutl, Wq, Wkv, Wouth,
                                         Wqkv_bf, Woutl_bf, Wq_bf, Wkv_bf, Wouth_bf);

  // fused LN + routing dots
  ln_sdot_kernel<<<16384, 256, 0, stream>>>(x, ln_w, ln_b, rtq, rtkv, ln_bf, s_d);

  // routing iterations + selection
  hipMemsetAsync(posq, 0xFF, 16384 * 4, stream);
  route_sel_kernel<<<8, 1024, 0, stream>>>(s_d, iq, ikv, posq);

  // light path
  gemm_bt<0><<<dim3(12, 128), 256, 0, stream>>>(ln_bf, Wqkv_bf, qkv_bf, 16384, 1536, 1024,
                                                nullptr, nullptr, nullptr);
  local_attn_kernel<<<dim3(64, 8, 4), 256, 0, stream>>>(qkv_bf, ol_bf);

  // heavy path
  gather_rms_kernel<<<6144, 256, 0, stream>>>(x, gamma, iq, ikv, xq_bf, xkv_bf);
  gemm_bt<0><<<dim3(4, 16), 256, 0, stream>>>(xq_bf, Wq_bf, qh_bf, 2048, 512, 1024,
                                              nullptr, nullptr, nullptr);
  gemm_bt<0><<<dim3(8, 32), 256, 0, stream>>>(xkv_bf, Wkv_bf, kvh_bf, 4096, 1024, 1024,
                                              nullptr, nullptr, nullptr);
  heavy_attn_split_kernel<<<dim3(8, 8, 16), 256, 0, stream>>>(qh_bf, kvh_bf, nkv, o_part, ml_part);
  heavy_combine_kernel<<<dim3(8, 8, 4), 256, 0, stream>>>(o_part, ml_part, oh_bf);
  gemm_bt<1><<<dim3(8, 16), 256, 0, stream>>>(oh_bf, Wouth_bf, heavy_f, 2048, 1024, 512,
                                              nullptr, nullptr, nullptr);

  // light output GEMM + fused combine (heavy scatter / null_q) -> d_out
  gemm_bt<2><<<dim3(8, 128), 256, 0, stream>>>(ol_bf, Woutl_bf, out, 16384, 1024, 512,
                                               posq, heavy_f, nq);
}

// Round 4
// 414.546 us; speedup vs baseline: 1.4879x; 1.0015x over previous
//
#include <hip/hip_runtime.h>
#include <hip/hip_bf16.h>

typedef __attribute__((ext_vector_type(8))) short bv8;
typedef __attribute__((ext_vector_type(4))) float fv4;
typedef __hip_bfloat16 bf16;

#define MFMA16(a,b,c) __builtin_amdgcn_mfma_f32_16x16x32_bf16((a),(b),(c),0,0,0)
#define GLOAD_LDS(gp, lp) __builtin_amdgcn_global_load_lds( \
    (const __attribute__((address_space(1))) void*)(gp), \
    (__attribute__((address_space(3))) void*)(lp), 16, 0, 0)

// ---------------- block reduce helpers ----------------
template<int NW>
__device__ __forceinline__ float blockReduceSumF(float v) {
  #pragma unroll
  for (int m = 1; m < 64; m <<= 1) v += __shfl_xor(v, m, 64);
  __shared__ float sm[NW];
  if ((threadIdx.x & 63) == 0) sm[threadIdx.x >> 6] = v;
  __syncthreads();
  float t = 0.f;
  #pragma unroll
  for (int i = 0; i < NW; ++i) t += sm[i];
  __syncthreads();
  return t;
}

template<int NW>
__device__ __forceinline__ double blockReduceSumD(double v) {
  #pragma unroll
  for (int m = 1; m < 64; m <<= 1) v += __shfl_xor(v, m, 64);
  __shared__ double sm[NW];
  if ((threadIdx.x & 63) == 0) sm[threadIdx.x >> 6] = v;
  __syncthreads();
  double t = 0.0;
  #pragma unroll
  for (int i = 0; i < NW; ++i) t += sm[i];
  __syncthreads();
  return t;
}

template<int NW>
__device__ __forceinline__ double blockReduceMaxD(double v) {
  #pragma unroll
  for (int m = 1; m < 64; m <<= 1) v = fmax(v, __shfl_xor(v, m, 64));
  __shared__ double sm[NW];
  if ((threadIdx.x & 63) == 0) sm[threadIdx.x >> 6] = v;
  __syncthreads();
  double t = sm[0];
  #pragma unroll
  for (int i = 1; i < NW; ++i) t = fmax(t, sm[i]);
  __syncthreads();
  return t;
}

// ---------------- fused weight cast (5 segments, 8 elems/thread) ----------------
__global__ __launch_bounds__(256)
void cast5_kernel(const float* __restrict__ a0, const float* __restrict__ a1,
                  const float* __restrict__ a2, const float* __restrict__ a3,
                  const float* __restrict__ a4,
                  bf16* __restrict__ b0, bf16* __restrict__ b1, bf16* __restrict__ b2,
                  bf16* __restrict__ b3, bf16* __restrict__ b4) {
  size_t g = ((size_t)blockIdx.x * 256 + threadIdx.x) * 8;
  const float* src; bf16* dst; size_t off;
  if (g < 1572864)      { src = a0; dst = b0; off = g; }
  else if (g < 2097152) { src = a1; dst = b1; off = g - 1572864; }
  else if (g < 2621440) { src = a2; dst = b2; off = g - 2097152; }
  else if (g < 3670016) { src = a3; dst = b3; off = g - 2621440; }
  else                  { src = a4; dst = b4; off = g - 3670016; }
  float4 v0 = *(const float4*)(src + off);
  float4 v1 = *(const float4*)(src + off + 4);
  bv8 o;
  ((bf16*)&o)[0] = __float2bfloat16(v0.x); ((bf16*)&o)[1] = __float2bfloat16(v0.y);
  ((bf16*)&o)[2] = __float2bfloat16(v0.z); ((bf16*)&o)[3] = __float2bfloat16(v0.w);
  ((bf16*)&o)[4] = __float2bfloat16(v1.x); ((bf16*)&o)[5] = __float2bfloat16(v1.y);
  ((bf16*)&o)[6] = __float2bfloat16(v1.z); ((bf16*)&o)[7] = __float2bfloat16(v1.w);
  *(bv8*)(dst + off) = o;
}

// Fused LayerNorm (-> bf16) + routing dot products (fp64)
__global__ __launch_bounds__(256)
void ln_sdot_kernel(const float* __restrict__ x, const float* __restrict__ w,
                    const float* __restrict__ bb, const float* __restrict__ rtq,
                    const float* __restrict__ rtkv, bf16* __restrict__ out,
                    double* __restrict__ s) {
  const int r = blockIdx.x;
  const float* xr = x + (size_t)r * 1024;
  float v4[4]; float ssum = 0.f;
  double dq = 0.0, dk = 0.0;
  #pragma unroll
  for (int i = 0; i < 4; ++i) {
    int d = threadIdx.x + i * 256;
    float v = xr[d];
    v4[i] = v; ssum += v;
    dq += (double)v * (double)rtq[d];
    dk += (double)v * (double)rtkv[d];
  }
  ssum = blockReduceSumF<4>(ssum);
  const float mean = ssum * (1.0f / 1024.0f);
  float vs = 0.f;
  #pragma unroll
  for (int i = 0; i < 4; ++i) { float d = v4[i] - mean; vs += d * d; }
  vs = blockReduceSumF<4>(vs);
  const float rstd = 1.0f / sqrtf(vs * (1.0f / 1024.0f) + 1e-5f);
  dq = blockReduceSumD<4>(dq);
  dk = blockReduceSumD<4>(dk);
  if (threadIdx.x == 0) { s[r] = dq; s[16384 + r] = dk; }
  bf16* orow = out + (size_t)r * 1024;
  #pragma unroll
  for (int i = 0; i < 4; ++i) {
    int d = threadIdx.x + i * 256;
    orow[d] = __float2bfloat16((v4[i] - mean) * rstd * w[d] + bb[d]);
  }
}

// Fused routing: 50 fixed-point iterations in LINEAR z-domain
//   z_{n+1} = (cnt(z)·z + Σ_{ev<z} ev)/K,  ev = exp(s - mx),  z = exp(-a - mx)
// (no per-iteration transcendentals), then threshold selection
// (prefix scan fast path; bitonic fallback).
__global__ __launch_bounds__(1024)
void route_sel_kernel(const double* __restrict__ s_all, int* __restrict__ iq,
                      int* __restrict__ ikv, int* __restrict__ posq) {
  const int route = blockIdx.x >> 2, b = blockIdx.x & 3;
  const double* s = s_all + route * 16384 + b * 4096;
  const double K = (route == 0) ? 576.0 : 1152.0;
  const int KSEL = (route == 0) ? 512 : 1024;
  const int tid = threadIdx.x;
  const int lane = tid & 63, wid = tid >> 6;
  double sv[4], ev[4];
  #pragma unroll
  for (int i = 0; i < 4; ++i) sv[i] = s[tid * 4 + i];
  double mx = fmax(fmax(sv[0], sv[1]), fmax(sv[2], sv[3]));
  mx = blockReduceMaxD<16>(mx);
  #pragma unroll
  for (int i = 0; i < 4; ++i) ev[i] = exp(sv[i] - mx);
  __shared__ double red[32];
  // body eval 1: bb=-s => lse = log(4096); a1 = logK - log(4096); z1 = exp(-a1-mx)
  double z = (4096.0 / K) * exp(-mx);
  for (int it = 1; it < 50; ++it) {
    double cnt = 0.0, us = 0.0;
    #pragma unroll
    for (int i = 0; i < 4; ++i) {
      if (ev[i] >= z) cnt += 1.0; else us += ev[i];
    }
    #pragma unroll
    for (int m = 1; m < 64; m <<= 1) { cnt += __shfl_xor(cnt, m, 64); us += __shfl_xor(us, m, 64); }
    if (lane == 0) { red[wid] = cnt; red[16 + wid] = us; }
    __syncthreads();
    double tc = 0.0, tu = 0.0;
    #pragma unroll
    for (int i = 0; i < 16; ++i) { tc += red[i]; tu += red[16 + i]; }
    z = (tc * z + tu) / K;       // all threads compute the same z redundantly
    __syncthreads();
  }
  const double a = -mx - log(z);
  // final scores (fp32, matching reference semantics incl. rounding-to-1.0f ties)
  float scf[4]; int m4 = 0;
  #pragma unroll
  for (int i = 0; i < 4; ++i) {
    double v = sv[i] + a;
    scf[i] = (float)exp(fmin(v, 0.0));
    m4 += (scf[i] == 1.0f) ? 1 : 0;
  }
  __shared__ int scn[1024];
  scn[tid] = m4;
  __syncthreads();
  for (int off = 1; off < 1024; off <<= 1) {
    int v = (tid >= off) ? scn[tid - off] : 0;
    __syncthreads();
    scn[tid] += v;
    __syncthreads();
  }
  const int total = scn[1023];
  const int excl = scn[tid] - m4;
  if (total >= KSEL) {
    // fast path: top-K = first K saturated (score==1.0f) in ascending index order
    int rk = excl;
    #pragma unroll
    for (int i = 0; i < 4; ++i) {
      if (scf[i] == 1.0f) {
        if (rk < KSEL) {
          int idx = tid * 4 + i;
          if (route == 0) { iq[b * 512 + rk] = idx; posq[b * 4096 + idx] = rk; }
          else            { ikv[b * 1024 + rk] = idx; }
        }
        rk++;
      }
    }
  } else {
    // fallback: full bitonic sort (score desc, index asc)
    __shared__ unsigned long long keys[4096];
    #pragma unroll
    for (int i = 0; i < 4; ++i) {
      unsigned bits = __float_as_uint(scf[i]);   // scores in [0,1] -> bits monotone
      keys[tid * 4 + i] = ((unsigned long long)(~bits) << 32) | (unsigned long long)(tid * 4 + i);
    }
    for (int k = 2; k <= 4096; k <<= 1) {
      for (int j = k >> 1; j > 0; j >>= 1) {
        __syncthreads();
        for (int t = tid; t < 2048; t += 1024) {
          int i2 = ((t & ~(j - 1)) << 1) | (t & (j - 1));
          int ip = i2 + j;
          unsigned long long av = keys[i2], bvv = keys[ip];
          bool up = ((i2 & k) == 0);
          if (up ? (av > bvv) : (av < bvv)) { keys[i2] = bvv; keys[ip] = av; }
        }
      }
    }
    __syncthreads();
    for (int j2 = tid; j2 < KSEL; j2 += 1024) {
      int idx = (int)(keys[j2] & 0xFFFFFFFFull);
      if (route == 0) { iq[b * 512 + j2] = idx; posq[b * 4096 + idx] = j2; }
      else            { ikv[b * 1024 + j2] = idx; }
    }
  }
}

// gather selected tokens + RMS norm -> bf16
__global__ __launch_bounds__(256)
void gather_rms_kernel(const float* __restrict__ x, const float* __restrict__ gamma,
                       const int* __restrict__ iq, const int* __restrict__ ikv,
                       bf16* __restrict__ xq, bf16* __restrict__ xkv) {
  const int bid = blockIdx.x;
  const float* src; bf16* dst;
  if (bid < 2048) {
    int b = bid >> 9, j = bid & 511;
    int tok = iq[b * 512 + j];
    src = x + ((size_t)(b * 4096 + tok)) * 1024;
    dst = xq + (size_t)bid * 1024;
  } else {
    int id = bid - 2048;
    int b = id >> 10, j = id & 1023;
    int tok = ikv[b * 1024 + j];
    src = x + ((size_t)(b * 4096 + tok)) * 1024;
    dst = xkv + (size_t)id * 1024;
  }
  float v4[4]; float ss = 0.f;
  #pragma unroll
  for (int i = 0; i < 4; ++i) { v4[i] = src[threadIdx.x + i * 256]; ss += v4[i] * v4[i]; }
  ss = blockReduceSumF<4>(ss);
  const float nrm = fmaxf(sqrtf(ss), 1e-12f);
  const float scl = 32.0f / nrm;
  #pragma unroll
  for (int i = 0; i < 4; ++i) {
    int d = threadIdx.x + i * 256;
    dst[d] = __float2bfloat16(v4[i] * scl * gamma[d]);
  }
}

// ---------------- GEMM: C(MxN) = A(MxK) * B(NxK)^T, bf16 in, fp32 acc ----------------
// m97-style: linear [128][32] LDS tiles staged via global_load_lds width 16.
// EPI: 0 = bf16 store, 1 = f32 store, 2 = f32 store + combine (light + heavy/null_q)
template<int EPI>
__global__ __launch_bounds__(256)
void gemm_bt(const bf16* __restrict__ A, const bf16* __restrict__ B, void* __restrict__ Cout,
             int M, int N, int K,
             const int* __restrict__ posq, const float* __restrict__ heavy,
             const float* __restrict__ nullq) {
  __shared__ alignas(16) bf16 As[128 * 32];
  __shared__ alignas(16) bf16 Bs[128 * 32];
  const int tid = threadIdx.x;
  const int lane = tid & 63, w = tid >> 6;
  const int wr = w >> 1, wc = w & 1;
  const int lrow = lane & 15, lk = (lane >> 4) * 8;
  const int row0 = blockIdx.y * 128, col0 = blockIdx.x * 128;
  fv4 acc[4][4];
  #pragma unroll
  for (int m = 0; m < 4; ++m)
    #pragma unroll
    for (int n = 0; n < 4; ++n) acc[m][n] = (fv4){0.f, 0.f, 0.f, 0.f};
  // per-lane staging source mapping (LDS linear: byte off = r*64 + c*16)
  const int ob0 = w * 2048;
  for (int k0 = 0; k0 < K; k0 += 32) {
    #pragma unroll
    for (int t = 0; t < 2; ++t) {
      int ob = ob0 + t * 1024;
      int ofl = ob + lane * 16;
      int r = ofl >> 6, c8 = ((ofl >> 4) & 3) * 8;
      GLOAD_LDS(A + (size_t)(row0 + r) * K + k0 + c8, (char*)As + ob);
      GLOAD_LDS(B + (size_t)(col0 + r) * K + k0 + c8, (char*)Bs + ob);
    }
    __syncthreads();   // drains vmcnt -> LDS tiles ready
    bv8 af[4], bfr[4];
    #pragma unroll
    for (int m = 0; m < 4; ++m) af[m] = *(bv8*)&As[(wr * 64 + m * 16 + lrow) * 32 + lk];
    #pragma unroll
    for (int n = 0; n < 4; ++n) bfr[n] = *(bv8*)&Bs[(wc * 64 + n * 16 + lrow) * 32 + lk];
    #pragma unroll
    for (int m = 0; m < 4; ++m)
      #pragma unroll
      for (int n = 0; n < 4; ++n)
        acc[m][n] = MFMA16(af[m], bfr[n], acc[m][n]);
    __syncthreads();
  }
  #pragma unroll
  for (int m = 0; m < 4; ++m) {
    int gr0 = row0 + wr * 64 + m * 16 + (lane >> 4) * 4;
    #pragma unroll
    for (int n = 0; n < 4; ++n) {
      int gc = col0 + wc * 64 + n * 16 + lrow;
      #pragma unroll
      for (int r = 0; r < 4; ++r) {
        int grow = gr0 + r;
        float vv = acc[m][n][r];
        if (EPI == 0) {
          ((bf16*)Cout)[(size_t)grow * N + gc] = __float2bfloat16(vv);
        } else if (EPI == 1) {
          ((float*)Cout)[(size_t)grow * N + gc] = vv;
        } else {
          int p = posq[grow];
          float add = (p >= 0) ? heavy[((size_t)((grow >> 12) * 512 + p)) * 1024 + gc]
                               : nullq[gc];
          ((float*)Cout)[(size_t)grow * N + gc] = vv + add;
        }
      }
    }
  }
}

// ---------------- local windowed attention (flash over 3 windows) ----------------
__global__ __launch_bounds__(256)
void local_attn_kernel(const bf16* __restrict__ qkv, bf16* __restrict__ olight) {
  const int w = blockIdx.x, h = blockIdx.y, b = blockIdx.z;
  const int tid = threadIdx.x;
  const int lane = tid & 63, wv = tid >> 6;
  const int lrow = lane & 15, lkg = lane >> 4;
  __shared__ bf16 Qs[64][72], Ks[64][72], Vts[64][72], Ps[64][72];
  {
    const size_t baseq = ((size_t)(b * 4096 + w * 64)) * 1536 + h * 64;
    #pragma unroll
    for (int v = 0; v < 2; ++v) {
      int vec = tid + v * 256; int i = vec >> 3, dd = (vec & 7) * 8;
      *(bv8*)&Qs[i][dd] = *(const bv8*)&qkv[baseq + (size_t)i * 1536 + dd];
    }
  }
  fv4 oacc[4];
  float m_run[4], l_run[4];
  #pragma unroll
  for (int n = 0; n < 4; ++n) oacc[n] = (fv4){0.f, 0.f, 0.f, 0.f};
  #pragma unroll
  for (int r = 0; r < 4; ++r) { m_run[r] = -INFINITY; l_run[r] = 0.f; }
  for (int c = 0; c < 3; ++c) {
    int sw = w - 1 + c;
    if (sw < 0 || sw >= 64) continue;           // uniform across block
    __syncthreads();
    const size_t bkv = ((size_t)(b * 4096 + sw * 64)) * 1536 + h * 64;
    #pragma unroll
    for (int v = 0; v < 2; ++v) {
      int vec = tid + v * 256; int i = vec >> 3, dd = (vec & 7) * 8;
      *(bv8*)&Ks[i][dd] = *(const bv8*)&qkv[bkv + 512 + (size_t)i * 1536 + dd];
    }
    for (int e = tid; e < 4096; e += 256) {
      int j = e >> 6, dd = e & 63;
      Vts[dd][j] = qkv[bkv + 1024 + (size_t)j * 1536 + dd];
    }
    __syncthreads();
    fv4 sa[4];
    #pragma unroll
    for (int n = 0; n < 4; ++n) {
      sa[n] = (fv4){0.f, 0.f, 0.f, 0.f};
      #pragma unroll
      for (int ks = 0; ks < 2; ++ks) {
        bv8 aq = *(bv8*)&Qs[wv * 16 + lrow][lkg * 8 + ks * 32];
        bv8 bk = *(bv8*)&Ks[n * 16 + lrow][lkg * 8 + ks * 32];
        sa[n] = MFMA16(aq, bk, sa[n]);
      }
    }
    float mc[4];
    #pragma unroll
    for (int r = 0; r < 4; ++r) {
      #pragma unroll
      for (int n = 0; n < 4; ++n) sa[n][r] *= 0.125f;
      mc[r] = fmaxf(fmaxf(sa[0][r], sa[1][r]), fmaxf(sa[2][r], sa[3][r]));
    }
    #pragma unroll
    for (int m = 1; m < 16; m <<= 1)
      #pragma unroll
      for (int r = 0; r < 4; ++r) mc[r] = fmaxf(mc[r], __shfl_xor(mc[r], m, 64));
    float p[4][4], ls[4];
    #pragma unroll
    for (int r = 0; r < 4; ++r) {
      float mn = fmaxf(m_run[r], mc[r]);
      float scl = expf(m_run[r] - mn);
      ls[r] = 0.f;
      #pragma unroll
      for (int n = 0; n < 4; ++n) { p[n][r] = expf(sa[n][r] - mn); ls[r] += p[n][r]; }
      m_run[r] = mn;
      l_run[r] *= scl;
      #pragma unroll
      for (int n = 0; n < 4; ++n) oacc[n][r] *= scl;
    }
    #pragma unroll
    for (int m = 1; m < 16; m <<= 1)
      #pragma unroll
      for (int r = 0; r < 4; ++r) ls[r] += __shfl_xor(ls[r], m, 64);
    #pragma unroll
    for (int r = 0; r < 4; ++r) l_run[r] += ls[r];
    #pragma unroll
    for (int n = 0; n < 4; ++n)
      #pragma unroll
      for (int r = 0; r < 4; ++r)
        Ps[wv * 16 + lkg * 4 + r][n * 16 + lrow] = __float2bfloat16(p[n][r]);
    __syncthreads();
    #pragma unroll
    for (int n = 0; n < 4; ++n)
      #pragma unroll
      for (int ks = 0; ks < 2; ++ks) {
        bv8 ap = *(bv8*)&Ps[wv * 16 + lrow][lkg * 8 + ks * 32];
        bv8 bvv = *(bv8*)&Vts[n * 16 + lrow][lkg * 8 + ks * 32];
        oacc[n] = MFMA16(ap, bvv, oacc[n]);
      }
  }
  const size_t ob = ((size_t)(b * 4096 + w * 64 + wv * 16)) * 512 + h * 64;
  #pragma unroll
  for (int n = 0; n < 4; ++n)
    #pragma unroll
    for (int r = 0; r < 4; ++r) {
      int row = lkg * 4 + r;
      olight[ob + (size_t)row * 512 + n * 16 + lrow] = __float2bfloat16(oacc[n][r] / l_run[r]);
    }
}

// ---------------- heavy attention: split-K flash partials ----------------
// blockIdx: x=qt(8), y=h(8), z=b*4+split
// split 0: tiles 0..4 (incl null at kvg=0); split s: tiles s*4+1 .. s*4+4
__global__ __launch_bounds__(256)
void heavy_attn_split_kernel(const bf16* __restrict__ qh, const bf16* __restrict__ kvh,
                             const float* __restrict__ nkv, float* __restrict__ o_part,
                             float* __restrict__ ml_part) {
  const int qt = blockIdx.x, h = blockIdx.y;
  const int b = blockIdx.z >> 2, s = blockIdx.z & 3;
  const int tid = threadIdx.x;
  const int lane = tid & 63, wv = tid >> 6;
  const int lrow = lane & 15, lkg = lane >> 4;
  __shared__ bf16 Qs[64][72], Ks[64][72], Vts[64][72], Ps[64][72];
  {
    const size_t baseq = ((size_t)(b * 512 + qt * 64)) * 512 + h * 64;
    #pragma unroll
    for (int v = 0; v < 2; ++v) {
      int vec = tid + v * 256; int i = vec >> 3, dd = (vec & 7) * 8;
      *(bv8*)&Qs[i][dd] = *(const bv8*)&qh[baseq + (size_t)i * 512 + dd];
    }
  }
  fv4 oacc[4];
  float m_run[4], l_run[4];
  #pragma unroll
  for (int n = 0; n < 4; ++n) oacc[n] = (fv4){0.f, 0.f, 0.f, 0.f};
  #pragma unroll
  for (int r = 0; r < 4; ++r) { m_run[r] = -INFINITY; l_run[r] = 0.f; }
  const int cs = (s == 0) ? 0 : (s * 4 + 1);
  const int ce = s * 4 + 5;
  for (int c = cs; c < ce; ++c) {
    __syncthreads();
    #pragma unroll
    for (int v = 0; v < 2; ++v) {
      int vec = tid + v * 256; int j = vec >> 3, dd = (vec & 7) * 8;
      int kvg = c * 64 + j;
      bv8 val;
      if (kvg >= 1 && kvg <= 1024) {
        val = *(const bv8*)&kvh[((size_t)(b * 1024 + kvg - 1)) * 1024 + h * 128 + dd];
      } else if (kvg == 0) {
        #pragma unroll
        for (int t = 0; t < 8; ++t) ((bf16*)&val)[t] = __float2bfloat16(nkv[h * 64 + dd + t]);
      } else {
        #pragma unroll
        for (int t = 0; t < 8; ++t) ((short*)&val)[t] = 0;
      }
      *(bv8*)&Ks[j][dd] = val;
    }
    for (int e = tid; e < 4096; e += 256) {
      int j = e >> 6, dd = e & 63;
      int kvg = c * 64 + j;
      bf16 vvv;
      if (kvg >= 1 && kvg <= 1024)
        vvv = kvh[((size_t)(b * 1024 + kvg - 1)) * 1024 + h * 128 + 64 + dd];
      else if (kvg == 0)
        vvv = __float2bfloat16(nkv[512 + h * 64 + dd]);
      else
        vvv = __float2bfloat16(0.0f);
      Vts[dd][j] = vvv;
    }
    __syncthreads();
    fv4 sa[4];
    #pragma unroll
    for (int n = 0; n < 4; ++n) {
      sa[n] = (fv4){0.f, 0.f, 0.f, 0.f};
      #pragma unroll
      for (int ks = 0; ks < 2; ++ks) {
        bv8 aq = *(bv8*)&Qs[wv * 16 + lrow][lkg * 8 + ks * 32];
        bv8 bk = *(bv8*)&Ks[n * 16 + lrow][lkg * 8 + ks * 32];
        sa[n] = MFMA16(aq, bk, sa[n]);
      }
    }
    float mc[4];
    #pragma unroll
    for (int r = 0; r < 4; ++r) {
      #pragma unroll
      for (int n = 0; n < 4; ++n) {
        sa[n][r] *= 0.125f;
        int kvg = c * 64 + n * 16 + lrow;
        if (kvg > 1024) sa[n][r] = -1e30f;
      }
      mc[r] = fmaxf(fmaxf(sa[0][r], sa[1][r]), fmaxf(sa[2][r], sa[3][r]));
    }
    #pragma unroll
    for (int m = 1; m < 16; m <<= 1)
      #pragma unroll
      for (int r = 0; r < 4; ++r) mc[r] = fmaxf(mc[r], __shfl_xor(mc[r], m, 64));
    float p[4][4], ls[4];
    #pragma unroll
    for (int r = 0; r < 4; ++r) {
      float mn = fmaxf(m_run[r], mc[r]);
      float scl = expf(m_run[r] - mn);
      ls[r] = 0.f;
      #pragma unroll
      for (int n = 0; n < 4; ++n) { p[n][r] = expf(sa[n][r] - mn); ls[r] += p[n][r]; }
      m_run[r] = mn;
      l_run[r] *= scl;
      #pragma unroll
      for (int n = 0; n < 4; ++n) oacc[n][r] *= scl;
    }
    #pragma unroll
    for (int m = 1; m < 16; m <<= 1)
      #pragma unroll
      for (int r = 0; r < 4; ++r) ls[r] += __shfl_xor(ls[r], m, 64);
    #pragma unroll
    for (int r = 0; r < 4; ++r) l_run[r] += ls[r];
    #pragma unroll
    for (int n = 0; n < 4; ++n)
      #pragma unroll
      for (int r = 0; r < 4; ++r)
        Ps[wv * 16 + lkg * 4 + r][n * 16 + lrow] = __float2bfloat16(p[n][r]);
    __syncthreads();
    #pragma unroll
    for (int n = 0; n < 4; ++n)
      #pragma unroll
      for (int ks = 0; ks < 2; ++ks) {
        bv8 ap = *(bv8*)&Ps[wv * 16 + lrow][lkg * 8 + ks * 32];
        bv8 bvv = *(bv8*)&Vts[n * 16 + lrow][lkg * 8 + ks * 32];
        oacc[n] = MFMA16(ap, bvv, oacc[n]);
      }
  }
  // store partials (no normalization)
  const int idx = (((s * 4 + b) * 8 + h) * 8 + qt);
  float* ob = o_part + (size_t)idx * 4096;
  #pragma unroll
  for (int n = 0; n < 4; ++n)
    #pragma unroll
    for (int r = 0; r < 4; ++r) {
      int row = wv * 16 + lkg * 4 + r;
      ob[row * 64 + n * 16 + lrow] = oacc[n][r];
    }
  if (lrow == 0) {
    #pragma unroll
    for (int r = 0; r < 4; ++r) {
      int row = wv * 16 + lkg * 4 + r;
      ml_part[idx * 128 + row] = m_run[r];
      ml_part[idx * 128 + 64 + row] = l_run[r];
    }
  }
}

// combine split partials -> bf16 heavy attention output
__global__ __launch_bounds__(256)
void heavy_combine_kernel(const float* __restrict__ o_part, const float* __restrict__ ml_part,
                          bf16* __restrict__ oh) {
  const int qt = blockIdx.x, h = blockIdx.y, b = blockIdx.z;
  const int tid = threadIdx.x;
  const int row = tid >> 2, c0 = (tid & 3) * 16;
  int idx[4]; float m[4], l[4];
  #pragma unroll
  for (int s = 0; s < 4; ++s) {
    idx[s] = (((s * 4 + b) * 8 + h) * 8 + qt);
    m[s] = ml_part[idx[s] * 128 + row];
    l[s] = ml_part[idx[s] * 128 + 64 + row];
  }
  const float mstar = fmaxf(fmaxf(m[0], m[1]), fmaxf(m[2], m[3]));
  float wsum = 0.f, w[4];
  #pragma unroll
  for (int s = 0; s < 4; ++s) { w[s] = expf(m[s] - mstar); wsum += w[s] * l[s]; }
  const float inv = 1.0f / wsum;
  float o[16];
  #pragma unroll
  for (int i = 0; i < 16; ++i) o[i] = 0.f;
  #pragma unroll
  for (int s = 0; s < 4; ++s) {
    const fv4* op = (const fv4*)(o_part + (size_t)idx[s] * 4096 + row * 64 + c0);
    #pragma unroll
    for (int k = 0; k < 4; ++k) {
      fv4 v = op[k];
      #pragma unroll
      for (int j = 0; j < 4; ++j) o[k * 4 + j] += w[s] * v[j];
    }
  }
  const size_t ob = ((size_t)(b * 512 + qt * 64 + row)) * 512 + h * 64 + c0;
  bv8 pk[2];
  #pragma unroll
  for (int i = 0; i < 16; ++i) ((bf16*)pk)[i] = __float2bfloat16(o[i] * inv);
  *(bv8*)&oh[ob] = pk[0];
  *(bv8*)&oh[ob + 8] = pk[1];
}

// ---------------- launcher ----------------
extern "C" void kernel_launch(void* const* d_in, const int* in_sizes, int n_in,
                              void* d_out, int out_size, void* d_ws, size_t ws_size,
                              hipStream_t stream) {
  (void)in_sizes; (void)n_in; (void)out_size; (void)ws_size;
  const float* x     = (const float*)d_in[0];
  const float* ln_w  = (const float*)d_in[1];
  const float* ln_b  = (const float*)d_in[2];
  const float* Wqkv  = (const float*)d_in[3];
  const float* Woutl = (const float*)d_in[4];
  const float* rtq   = (const float*)d_in[5];
  const float* rtkv  = (const float*)d_in[6];
  const float* gamma = (const float*)d_in[7];
  const float* Wq    = (const float*)d_in[8];
  const float* Wkv   = (const float*)d_in[9];
  const float* Wouth = (const float*)d_in[10];
  const float* nkv   = (const float*)d_in[11];
  const float* nq    = (const float*)d_in[12];
  float* out = (float*)d_out;

  char* ws = (char*)d_ws;
  size_t off = 0;
  auto alloc = [&](size_t bytes) -> void* {
    void* p = ws + off;
    off = (off + bytes + 255) & ~(size_t)255;
    return p;
  };
  bf16* ln_bf    = (bf16*)alloc(16384ull * 1024 * 2);
  bf16* qkv_bf   = (bf16*)alloc(16384ull * 1536 * 2);
  bf16* ol_bf    = (bf16*)alloc(16384ull * 512 * 2);
  bf16* Wqkv_bf  = (bf16*)alloc(1536ull * 1024 * 2);
  bf16* Woutl_bf = (bf16*)alloc(1024ull * 512 * 2);
  bf16* Wq_bf    = (bf16*)alloc(512ull * 1024 * 2);
  bf16* Wkv_bf   = (bf16*)alloc(1024ull * 1024 * 2);
  bf16* Wouth_bf = (bf16*)alloc(1024ull * 512 * 2);
  double* s_d    = (double*)alloc(32768ull * 8);
  int* iq        = (int*)alloc(2048ull * 4);
  int* ikv       = (int*)alloc(4096ull * 4);
  int* posq      = (int*)alloc(16384ull * 4);
  bf16* xq_bf    = (bf16*)alloc(2048ull * 1024 * 2);
  bf16* xkv_bf   = (bf16*)alloc(4096ull * 1024 * 2);
  bf16* qh_bf    = (bf16*)alloc(2048ull * 512 * 2);
  bf16* kvh_bf   = (bf16*)alloc(4096ull * 1024 * 2);
  bf16* oh_bf    = (bf16*)alloc(2048ull * 512 * 2);
  float* heavy_f = (float*)alloc(2048ull * 1024 * 4);
  float* o_part  = (float*)alloc(4096ull * 4096 * 4);   // 4 splits x 1024 tiles x 64x64 f32
  float* ml_part = (float*)alloc(4096ull * 128 * 4);

  // fused weight casts (4M elements total)
  cast5_kernel<<<2048, 256, 0, stream>>>(Wqkv, Woutl, Wq, Wkv, Wouth,
                                         Wqkv_bf, Woutl_bf, Wq_bf, Wkv_bf, Wouth_bf);

  // fused LN + routing dots
  ln_sdot_kernel<<<16384, 256, 0, stream>>>(x, ln_w, ln_b, rtq, rtkv, ln_bf, s_d);

  // routing iterations + selection
  hipMemsetAsync(posq, 0xFF, 16384 * 4, stream);
  route_sel_kernel<<<8, 1024, 0, stream>>>(s_d, iq, ikv, posq);

  // light path
  gemm_bt<0><<<dim3(12, 128), 256, 0, stream>>>(ln_bf, Wqkv_bf, qkv_bf, 16384, 1536, 1024,
                                                nullptr, nullptr, nullptr);
  local_attn_kernel<<<dim3(64, 8, 4), 256, 0, stream>>>(qkv_bf, ol_bf);

  // heavy path
  gather_rms_kernel<<<6144, 256, 0, stream>>>(x, gamma, iq, ikv, xq_bf, xkv_bf);
  gemm_bt<0><<<dim3(4, 16), 256, 0, stream>>>(xq_bf, Wq_bf, qh_bf, 2048, 512, 1024,
                                              nullptr, nullptr, nullptr);
  gemm_bt<0><<<dim3(8, 32), 256, 0, stream>>>(xkv_bf, Wkv_bf, kvh_bf, 4096, 1024, 1024,
                                              nullptr, nullptr, nullptr);
  heavy_attn_split_kernel<<<dim3(8, 8, 16), 256, 0, stream>>>(qh_bf, kvh_bf, nkv, o_part, ml_part);
  heavy_combine_kernel<<<dim3(8, 8, 4), 256, 0, stream>>>(o_part, ml_part, oh_bf);
  gemm_bt<1><<<dim3(8, 16), 256, 0, stream>>>(oh_bf, Wouth_bf, heavy_f, 2048, 1024, 512,
                                              nullptr, nullptr, nullptr);

  // light output GEMM + fused combine (heavy scatter / null_q) -> d_out
  gemm_bt<2><<<dim3(8, 128), 256, 0, stream>>>(ol_bf, Woutl_bf, out, 16384, 1024, 512,
                                               posq, heavy_f, nq);
}

// Round 5
// 350.294 us; speedup vs baseline: 1.7608x; 1.1834x over previous
//
#include <hip/hip_runtime.h>
#include <hip/hip_bf16.h>

typedef __attribute__((ext_vector_type(8))) short bv8;
typedef __attribute__((ext_vector_type(4))) float fv4;
typedef __hip_bfloat16 bf16;

#define MFMA16(a,b,c) __builtin_amdgcn_mfma_f32_16x16x32_bf16((a),(b),(c),0,0,0)
#define GLOAD_LDS(gp, lp) __builtin_amdgcn_global_load_lds( \
    (const __attribute__((address_space(1))) void*)(gp), \
    (__attribute__((address_space(3))) void*)(lp), 16, 0, 0)

// ---------------- block reduce helpers ----------------
template<int NW>
__device__ __forceinline__ float blockReduceSumF(float v) {
  #pragma unroll
  for (int m = 1; m < 64; m <<= 1) v += __shfl_xor(v, m, 64);
  __shared__ float sm[NW];
  if ((threadIdx.x & 63) == 0) sm[threadIdx.x >> 6] = v;
  __syncthreads();
  float t = 0.f;
  #pragma unroll
  for (int i = 0; i < NW; ++i) t += sm[i];
  __syncthreads();
  return t;
}

template<int NW>
__device__ __forceinline__ double blockReduceSumD(double v) {
  #pragma unroll
  for (int m = 1; m < 64; m <<= 1) v += __shfl_xor(v, m, 64);
  __shared__ double sm[NW];
  if ((threadIdx.x & 63) == 0) sm[threadIdx.x >> 6] = v;
  __syncthreads();
  double t = 0.0;
  #pragma unroll
  for (int i = 0; i < NW; ++i) t += sm[i];
  __syncthreads();
  return t;
}

template<int NW>
__device__ __forceinline__ double blockReduceMaxD(double v) {
  #pragma unroll
  for (int m = 1; m < 64; m <<= 1) v = fmax(v, __shfl_xor(v, m, 64));
  __shared__ double sm[NW];
  if ((threadIdx.x & 63) == 0) sm[threadIdx.x >> 6] = v;
  __syncthreads();
  double t = sm[0];
  #pragma unroll
  for (int i = 1; i < NW; ++i) t = fmax(t, sm[i]);
  __syncthreads();
  return t;
}

// ---------------- fused weight cast (5 segments, 8 elems/thread) ----------------
__global__ __launch_bounds__(256)
void cast5_kernel(const float* __restrict__ a0, const float* __restrict__ a1,
                  const float* __restrict__ a2, const float* __restrict__ a3,
                  const float* __restrict__ a4,
                  bf16* __restrict__ b0, bf16* __restrict__ b1, bf16* __restrict__ b2,
                  bf16* __restrict__ b3, bf16* __restrict__ b4) {
  size_t g = ((size_t)blockIdx.x * 256 + threadIdx.x) * 8;
  const float* src; bf16* dst; size_t off;
  if (g < 1572864)      { src = a0; dst = b0; off = g; }
  else if (g < 2097152) { src = a1; dst = b1; off = g - 1572864; }
  else if (g < 2621440) { src = a2; dst = b2; off = g - 2097152; }
  else if (g < 3670016) { src = a3; dst = b3; off = g - 2621440; }
  else                  { src = a4; dst = b4; off = g - 3670016; }
  float4 v0 = *(const float4*)(src + off);
  float4 v1 = *(const float4*)(src + off + 4);
  bv8 o;
  ((bf16*)&o)[0] = __float2bfloat16(v0.x); ((bf16*)&o)[1] = __float2bfloat16(v0.y);
  ((bf16*)&o)[2] = __float2bfloat16(v0.z); ((bf16*)&o)[3] = __float2bfloat16(v0.w);
  ((bf16*)&o)[4] = __float2bfloat16(v1.x); ((bf16*)&o)[5] = __float2bfloat16(v1.y);
  ((bf16*)&o)[6] = __float2bfloat16(v1.z); ((bf16*)&o)[7] = __float2bfloat16(v1.w);
  *(bv8*)(dst + off) = o;
}

// Fused LayerNorm (-> bf16) + routing dot products (fp64)
__global__ __launch_bounds__(256)
void ln_sdot_kernel(const float* __restrict__ x, const float* __restrict__ w,
                    const float* __restrict__ bb, const float* __restrict__ rtq,
                    const float* __restrict__ rtkv, bf16* __restrict__ out,
                    double* __restrict__ s) {
  const int r = blockIdx.x;
  const float* xr = x + (size_t)r * 1024;
  float v4[4]; float ssum = 0.f;
  double dq = 0.0, dk = 0.0;
  #pragma unroll
  for (int i = 0; i < 4; ++i) {
    int d = threadIdx.x + i * 256;
    float v = xr[d];
    v4[i] = v; ssum += v;
    dq += (double)v * (double)rtq[d];
    dk += (double)v * (double)rtkv[d];
  }
  ssum = blockReduceSumF<4>(ssum);
  const float mean = ssum * (1.0f / 1024.0f);
  float vs = 0.f;
  #pragma unroll
  for (int i = 0; i < 4; ++i) { float d = v4[i] - mean; vs += d * d; }
  vs = blockReduceSumF<4>(vs);
  const float rstd = 1.0f / sqrtf(vs * (1.0f / 1024.0f) + 1e-5f);
  dq = blockReduceSumD<4>(dq);
  dk = blockReduceSumD<4>(dk);
  if (threadIdx.x == 0) { s[r] = dq; s[16384 + r] = dk; }
  bf16* orow = out + (size_t)r * 1024;
  #pragma unroll
  for (int i = 0; i < 4; ++i) {
    int d = threadIdx.x + i * 256;
    orow[d] = __float2bfloat16((v4[i] - mean) * rstd * w[d] + bb[d]);
  }
}

// Fused routing: 50 fixed-point iterations on ONE WAVE, register-resident:
//   z_{n+1} = (Σ_j min(ev_j, z_n)) / K,   ev = exp(s - mx),  z = exp(-a - mx)
// then threshold selection (prefix scan fast path; bitonic fallback).
// Block = 256 threads; wave 0 holds all 4096 ev in regs (64 fp64/lane).
__global__ __launch_bounds__(256, 1)
void route_sel_kernel(const double* __restrict__ s_all, int* __restrict__ iq,
                      int* __restrict__ ikv, int* __restrict__ posq) {
  const int route = blockIdx.x >> 2, b = blockIdx.x & 3;
  const double* s = s_all + route * 16384 + b * 4096;
  const double K = (route == 0) ? 576.0 : 1152.0;
  const int KSEL = (route == 0) ? 512 : 1024;
  const int tid = threadIdx.x;
  const int lane = tid & 63, wid = tid >> 6;
  __shared__ double evbuf[4096];          // transfer buffer; later aliased as sort keys
  __shared__ double a_sh;
  __shared__ int scn[256];

  // per-thread 16 contiguous tokens (ascending-index ownership for selection)
  double sv[16];
  #pragma unroll
  for (int i = 0; i < 16; ++i) sv[i] = s[tid * 16 + i];
  double mx = sv[0];
  #pragma unroll
  for (int i = 1; i < 16; ++i) mx = fmax(mx, sv[i]);
  mx = blockReduceMaxD<4>(mx);
  #pragma unroll
  for (int i = 0; i < 16; ++i) evbuf[tid * 16 + i] = exp(sv[i] - mx);
  __syncthreads();

  if (wid == 0) {
    // wave 0: gather all 4096 ev into registers (lane l owns tokens {l, 64+l, ...})
    double e64[64];
    #pragma unroll
    for (int j = 0; j < 64; ++j) e64[j] = evbuf[j * 64 + lane];
    double z = (4096.0 / K) * exp(-mx);   // iteration 1 closed form
    for (int it = 1; it < 50; ++it) {
      double a0 = 0.0, a1 = 0.0, a2 = 0.0, a3 = 0.0;
      #pragma unroll
      for (int j = 0; j < 64; j += 4) {
        a0 += fmin(e64[j], z);
        a1 += fmin(e64[j + 1], z);
        a2 += fmin(e64[j + 2], z);
        a3 += fmin(e64[j + 3], z);
      }
      double t = (a0 + a1) + (a2 + a3);
      #pragma unroll
      for (int m = 1; m < 64; m <<= 1) t += __shfl_xor(t, m, 64);
      z = t / K;
    }
    if (lane == 0) a_sh = -mx - log(z);
  }
  __syncthreads();
  const double a = a_sh;

  // final scores (fp32, matching reference semantics incl. rounding-to-1.0f ties)
  float scf[16]; int m16 = 0;
  #pragma unroll
  for (int i = 0; i < 16; ++i) {
    scf[i] = (float)exp(fmin(sv[i] + a, 0.0));
    m16 += (scf[i] == 1.0f) ? 1 : 0;
  }
  scn[tid] = m16;
  __syncthreads();
  for (int off = 1; off < 256; off <<= 1) {
    int v = (tid >= off) ? scn[tid - off] : 0;
    __syncthreads();
    scn[tid] += v;
    __syncthreads();
  }
  const int total = scn[255];
  const int excl = scn[tid] - m16;
  if (total >= KSEL) {
    // fast path: top-K = first K saturated (score==1.0f) in ascending index order
    int rk = excl;
    #pragma unroll
    for (int i = 0; i < 16; ++i) {
      if (scf[i] == 1.0f) {
        if (rk < KSEL) {
          int idx = tid * 16 + i;
          if (route == 0) { iq[b * 512 + rk] = idx; posq[b * 4096 + idx] = rk; }
          else            { ikv[b * 1024 + rk] = idx; }
        }
        rk++;
      }
    }
  } else {
    // fallback: full bitonic sort (score desc, index asc) on keys aliased over evbuf
    unsigned long long* keys = (unsigned long long*)evbuf;
    #pragma unroll
    for (int i = 0; i < 16; ++i) {
      unsigned bits = __float_as_uint(scf[i]);   // scores in [0,1] -> bits monotone
      keys[tid * 16 + i] = ((unsigned long long)(~bits) << 32) | (unsigned long long)(tid * 16 + i);
    }
    for (int k = 2; k <= 4096; k <<= 1) {
      for (int j = k >> 1; j > 0; j >>= 1) {
        __syncthreads();
        for (int t = tid; t < 2048; t += 256) {
          int i2 = ((t & ~(j - 1)) << 1) | (t & (j - 1));
          int ip = i2 + j;
          unsigned long long av = keys[i2], bvv = keys[ip];
          bool up = ((i2 & k) == 0);
          if (up ? (av > bvv) : (av < bvv)) { keys[i2] = bvv; keys[ip] = av; }
        }
      }
    }
    __syncthreads();
    for (int j2 = tid; j2 < KSEL; j2 += 256) {
      int idx = (int)(keys[j2] & 0xFFFFFFFFull);
      if (route == 0) { iq[b * 512 + j2] = idx; posq[b * 4096 + idx] = j2; }
      else            { ikv[b * 1024 + j2] = idx; }
    }
  }
}

// gather selected tokens + RMS norm -> bf16
__global__ __launch_bounds__(256)
void gather_rms_kernel(const float* __restrict__ x, const float* __restrict__ gamma,
                       const int* __restrict__ iq, const int* __restrict__ ikv,
                       bf16* __restrict__ xq, bf16* __restrict__ xkv) {
  const int bid = blockIdx.x;
  const float* src; bf16* dst;
  if (bid < 2048) {
    int b = bid >> 9, j = bid & 511;
    int tok = iq[b * 512 + j];
    src = x + ((size_t)(b * 4096 + tok)) * 1024;
    dst = xq + (size_t)bid * 1024;
  } else {
    int id = bid - 2048;
    int b = id >> 10, j = id & 1023;
    int tok = ikv[b * 1024 + j];
    src = x + ((size_t)(b * 4096 + tok)) * 1024;
    dst = xkv + (size_t)id * 1024;
  }
  float v4[4]; float ss = 0.f;
  #pragma unroll
  for (int i = 0; i < 4; ++i) { v4[i] = src[threadIdx.x + i * 256]; ss += v4[i] * v4[i]; }
  ss = blockReduceSumF<4>(ss);
  const float nrm = fmaxf(sqrtf(ss), 1e-12f);
  const float scl = 32.0f / nrm;
  #pragma unroll
  for (int i = 0; i < 4; ++i) {
    int d = threadIdx.x + i * 256;
    dst[d] = __float2bfloat16(v4[i] * scl * gamma[d]);
  }
}

// ---------------- GEMM: C(MxN) = A(MxK) * B(NxK)^T, bf16 in, fp32 acc ----------------
// m97-style: linear [128][32] LDS tiles staged via global_load_lds width 16.
// EPI: 0 = bf16 store, 1 = f32 store, 2 = f32 store + combine (light + heavy/null_q)
template<int EPI>
__global__ __launch_bounds__(256)
void gemm_bt(const bf16* __restrict__ A, const bf16* __restrict__ B, void* __restrict__ Cout,
             int M, int N, int K,
             const int* __restrict__ posq, const float* __restrict__ heavy,
             const float* __restrict__ nullq) {
  __shared__ alignas(16) bf16 As[128 * 32];
  __shared__ alignas(16) bf16 Bs[128 * 32];
  const int tid = threadIdx.x;
  const int lane = tid & 63, w = tid >> 6;
  const int wr = w >> 1, wc = w & 1;
  const int lrow = lane & 15, lk = (lane >> 4) * 8;
  const int row0 = blockIdx.y * 128, col0 = blockIdx.x * 128;
  fv4 acc[4][4];
  #pragma unroll
  for (int m = 0; m < 4; ++m)
    #pragma unroll
    for (int n = 0; n < 4; ++n) acc[m][n] = (fv4){0.f, 0.f, 0.f, 0.f};
  // per-lane staging source mapping (LDS linear: byte off = r*64 + c*16)
  const int ob0 = w * 2048;
  for (int k0 = 0; k0 < K; k0 += 32) {
    #pragma unroll
    for (int t = 0; t < 2; ++t) {
      int ob = ob0 + t * 1024;
      int ofl = ob + lane * 16;
      int r = ofl >> 6, c8 = ((ofl >> 4) & 3) * 8;
      GLOAD_LDS(A + (size_t)(row0 + r) * K + k0 + c8, (char*)As + ob);
      GLOAD_LDS(B + (size_t)(col0 + r) * K + k0 + c8, (char*)Bs + ob);
    }
    __syncthreads();   // drains vmcnt -> LDS tiles ready
    bv8 af[4], bfr[4];
    #pragma unroll
    for (int m = 0; m < 4; ++m) af[m] = *(bv8*)&As[(wr * 64 + m * 16 + lrow) * 32 + lk];
    #pragma unroll
    for (int n = 0; n < 4; ++n) bfr[n] = *(bv8*)&Bs[(wc * 64 + n * 16 + lrow) * 32 + lk];
    #pragma unroll
    for (int m = 0; m < 4; ++m)
      #pragma unroll
      for (int n = 0; n < 4; ++n)
        acc[m][n] = MFMA16(af[m], bfr[n], acc[m][n]);
    __syncthreads();
  }
  #pragma unroll
  for (int m = 0; m < 4; ++m) {
    int gr0 = row0 + wr * 64 + m * 16 + (lane >> 4) * 4;
    #pragma unroll
    for (int n = 0; n < 4; ++n) {
      int gc = col0 + wc * 64 + n * 16 + lrow;
      #pragma unroll
      for (int r = 0; r < 4; ++r) {
        int grow = gr0 + r;
        float vv = acc[m][n][r];
        if (EPI == 0) {
          ((bf16*)Cout)[(size_t)grow * N + gc] = __float2bfloat16(vv);
        } else if (EPI == 1) {
          ((float*)Cout)[(size_t)grow * N + gc] = vv;
        } else {
          int p = posq[grow];
          float add = (p >= 0) ? heavy[((size_t)((grow >> 12) * 512 + p)) * 1024 + gc]
                               : nullq[gc];
          ((float*)Cout)[(size_t)grow * N + gc] = vv + add;
        }
      }
    }
  }
}

// ---------------- local windowed attention (flash over 3 windows) ----------------
__global__ __launch_bounds__(256)
void local_attn_kernel(const bf16* __restrict__ qkv, bf16* __restrict__ olight) {
  const int w = blockIdx.x, h = blockIdx.y, b = blockIdx.z;
  const int tid = threadIdx.x;
  const int lane = tid & 63, wv = tid >> 6;
  const int lrow = lane & 15, lkg = lane >> 4;
  __shared__ bf16 Qs[64][72], Ks[64][72], Vts[64][72], Ps[64][72];
  {
    const size_t baseq = ((size_t)(b * 4096 + w * 64)) * 1536 + h * 64;
    #pragma unroll
    for (int v = 0; v < 2; ++v) {
      int vec = tid + v * 256; int i = vec >> 3, dd = (vec & 7) * 8;
      *(bv8*)&Qs[i][dd] = *(const bv8*)&qkv[baseq + (size_t)i * 1536 + dd];
    }
  }
  fv4 oacc[4];
  float m_run[4], l_run[4];
  #pragma unroll
  for (int n = 0; n < 4; ++n) oacc[n] = (fv4){0.f, 0.f, 0.f, 0.f};
  #pragma unroll
  for (int r = 0; r < 4; ++r) { m_run[r] = -INFINITY; l_run[r] = 0.f; }
  for (int c = 0; c < 3; ++c) {
    int sw = w - 1 + c;
    if (sw < 0 || sw >= 64) continue;           // uniform across block
    __syncthreads();
    const size_t bkv = ((size_t)(b * 4096 + sw * 64)) * 1536 + h * 64;
    #pragma unroll
    for (int v = 0; v < 2; ++v) {
      int vec = tid + v * 256; int i = vec >> 3, dd = (vec & 7) * 8;
      *(bv8*)&Ks[i][dd] = *(const bv8*)&qkv[bkv + 512 + (size_t)i * 1536 + dd];
    }
    for (int e = tid; e < 4096; e += 256) {
      int j = e >> 6, dd = e & 63;
      Vts[dd][j] = qkv[bkv + 1024 + (size_t)j * 1536 + dd];
    }
    __syncthreads();
    fv4 sa[4];
    #pragma unroll
    for (int n = 0; n < 4; ++n) {
      sa[n] = (fv4){0.f, 0.f, 0.f, 0.f};
      #pragma unroll
      for (int ks = 0; ks < 2; ++ks) {
        bv8 aq = *(bv8*)&Qs[wv * 16 + lrow][lkg * 8 + ks * 32];
        bv8 bk = *(bv8*)&Ks[n * 16 + lrow][lkg * 8 + ks * 32];
        sa[n] = MFMA16(aq, bk, sa[n]);
      }
    }
    float mc[4];
    #pragma unroll
    for (int r = 0; r < 4; ++r) {
      #pragma unroll
      for (int n = 0; n < 4; ++n) sa[n][r] *= 0.125f;
      mc[r] = fmaxf(fmaxf(sa[0][r], sa[1][r]), fmaxf(sa[2][r], sa[3][r]));
    }
    #pragma unroll
    for (int m = 1; m < 16; m <<= 1)
      #pragma unroll
      for (int r = 0; r < 4; ++r) mc[r] = fmaxf(mc[r], __shfl_xor(mc[r], m, 64));
    float p[4][4], ls[4];
    #pragma unroll
    for (int r = 0; r < 4; ++r) {
      float mn = fmaxf(m_run[r], mc[r]);
      float scl = expf(m_run[r] - mn);
      ls[r] = 0.f;
      #pragma unroll
      for (int n = 0; n < 4; ++n) { p[n][r] = expf(sa[n][r] - mn); ls[r] += p[n][r]; }
      m_run[r] = mn;
      l_run[r] *= scl;
      #pragma unroll
      for (int n = 0; n < 4; ++n) oacc[n][r] *= scl;
    }
    #pragma unroll
    for (int m = 1; m < 16; m <<= 1)
      #pragma unroll
      for (int r = 0; r < 4; ++r) ls[r] += __shfl_xor(ls[r], m, 64);
    #pragma unroll
    for (int r = 0; r < 4; ++r) l_run[r] += ls[r];
    #pragma unroll
    for (int n = 0; n < 4; ++n)
      #pragma unroll
      for (int r = 0; r < 4; ++r)
        Ps[wv * 16 + lkg * 4 + r][n * 16 + lrow] = __float2bfloat16(p[n][r]);
    __syncthreads();
    #pragma unroll
    for (int n = 0; n < 4; ++n)
      #pragma unroll
      for (int ks = 0; ks < 2; ++ks) {
        bv8 ap = *(bv8*)&Ps[wv * 16 + lrow][lkg * 8 + ks * 32];
        bv8 bvv = *(bv8*)&Vts[n * 16 + lrow][lkg * 8 + ks * 32];
        oacc[n] = MFMA16(ap, bvv, oacc[n]);
      }
  }
  const size_t ob = ((size_t)(b * 4096 + w * 64 + wv * 16)) * 512 + h * 64;
  #pragma unroll
  for (int n = 0; n < 4; ++n)
    #pragma unroll
    for (int r = 0; r < 4; ++r) {
      int row = lkg * 4 + r;
      olight[ob + (size_t)row * 512 + n * 16 + lrow] = __float2bfloat16(oacc[n][r] / l_run[r]);
    }
}

// ---------------- heavy attention: split-K flash partials ----------------
// blockIdx: x=qt(8), y=h(8), z=b*4+split
// split 0: tiles 0..4 (incl null at kvg=0); split s: tiles s*4+1 .. s*4+4
__global__ __launch_bounds__(256)
void heavy_attn_split_kernel(const bf16* __restrict__ qh, const bf16* __restrict__ kvh,
                             const float* __restrict__ nkv, float* __restrict__ o_part,
                             float* __restrict__ ml_part) {
  const int qt = blockIdx.x, h = blockIdx.y;
  const int b = blockIdx.z >> 2, s = blockIdx.z & 3;
  const int tid = threadIdx.x;
  const int lane = tid & 63, wv = tid >> 6;
  const int lrow = lane & 15, lkg = lane >> 4;
  __shared__ bf16 Qs[64][72], Ks[64][72], Vts[64][72], Ps[64][72];
  {
    const size_t baseq = ((size_t)(b * 512 + qt * 64)) * 512 + h * 64;
    #pragma unroll
    for (int v = 0; v < 2; ++v) {
      int vec = tid + v * 256; int i = vec >> 3, dd = (vec & 7) * 8;
      *(bv8*)&Qs[i][dd] = *(const bv8*)&qh[baseq + (size_t)i * 512 + dd];
    }
  }
  fv4 oacc[4];
  float m_run[4], l_run[4];
  #pragma unroll
  for (int n = 0; n < 4; ++n) oacc[n] = (fv4){0.f, 0.f, 0.f, 0.f};
  #pragma unroll
  for (int r = 0; r < 4; ++r) { m_run[r] = -INFINITY; l_run[r] = 0.f; }
  const int cs = (s == 0) ? 0 : (s * 4 + 1);
  const int ce = s * 4 + 5;
  for (int c = cs; c < ce; ++c) {
    __syncthreads();
    #pragma unroll
    for (int v = 0; v < 2; ++v) {
      int vec = tid + v * 256; int j = vec >> 3, dd = (vec & 7) * 8;
      int kvg = c * 64 + j;
      bv8 val;
      if (kvg >= 1 && kvg <= 1024) {
        val = *(const bv8*)&kvh[((size_t)(b * 1024 + kvg - 1)) * 1024 + h * 128 + dd];
      } else if (kvg == 0) {
        #pragma unroll
        for (int t = 0; t < 8; ++t) ((bf16*)&val)[t] = __float2bfloat16(nkv[h * 64 + dd + t]);
      } else {
        #pragma unroll
        for (int t = 0; t < 8; ++t) ((short*)&val)[t] = 0;
      }
      *(bv8*)&Ks[j][dd] = val;
    }
    for (int e = tid; e < 4096; e += 256) {
      int j = e >> 6, dd = e & 63;
      int kvg = c * 64 + j;
      bf16 vvv;
      if (kvg >= 1 && kvg <= 1024)
        vvv = kvh[((size_t)(b * 1024 + kvg - 1)) * 1024 + h * 128 + 64 + dd];
      else if (kvg == 0)
        vvv = __float2bfloat16(nkv[512 + h * 64 + dd]);
      else
        vvv = __float2bfloat16(0.0f);
      Vts[dd][j] = vvv;
    }
    __syncthreads();
    fv4 sa[4];
    #pragma unroll
    for (int n = 0; n < 4; ++n) {
      sa[n] = (fv4){0.f, 0.f, 0.f, 0.f};
      #pragma unroll
      for (int ks = 0; ks < 2; ++ks) {
        bv8 aq = *(bv8*)&Qs[wv * 16 + lrow][lkg * 8 + ks * 32];
        bv8 bk = *(bv8*)&Ks[n * 16 + lrow][lkg * 8 + ks * 32];
        sa[n] = MFMA16(aq, bk, sa[n]);
      }
    }
    float mc[4];
    #pragma unroll
    for (int r = 0; r < 4; ++r) {
      #pragma unroll
      for (int n = 0; n < 4; ++n) {
        sa[n][r] *= 0.125f;
        int kvg = c * 64 + n * 16 + lrow;
        if (kvg > 1024) sa[n][r] = -1e30f;
      }
      mc[r] = fmaxf(fmaxf(sa[0][r], sa[1][r]), fmaxf(sa[2][r], sa[3][r]));
    }
    #pragma unroll
    for (int m = 1; m < 16; m <<= 1)
      #pragma unroll
      for (int r = 0; r < 4; ++r) mc[r] = fmaxf(mc[r], __shfl_xor(mc[r], m, 64));
    float p[4][4], ls[4];
    #pragma unroll
    for (int r = 0; r < 4; ++r) {
      float mn = fmaxf(m_run[r], mc[r]);
      float scl = expf(m_run[r] - mn);
      ls[r] = 0.f;
      #pragma unroll
      for (int n = 0; n < 4; ++n) { p[n][r] = expf(sa[n][r] - mn); ls[r] += p[n][r]; }
      m_run[r] = mn;
      l_run[r] *= scl;
      #pragma unroll
      for (int n = 0; n < 4; ++n) oacc[n][r] *= scl;
    }
    #pragma unroll
    for (int m = 1; m < 16; m <<= 1)
      #pragma unroll
      for (int r = 0; r < 4; ++r) ls[r] += __shfl_xor(ls[r], m, 64);
    #pragma unroll
    for (int r = 0; r < 4; ++r) l_run[r] += ls[r];
    #pragma unroll
    for (int n = 0; n < 4; ++n)
      #pragma unroll
      for (int r = 0; r < 4; ++r)
        Ps[wv * 16 + lkg * 4 + r][n * 16 + lrow] = __float2bfloat16(p[n][r]);
    __syncthreads();
    #pragma unroll
    for (int n = 0; n < 4; ++n)
      #pragma unroll
      for (int ks = 0; ks < 2; ++ks) {
        bv8 ap = *(bv8*)&Ps[wv * 16 + lrow][lkg * 8 + ks * 32];
        bv8 bvv = *(bv8*)&Vts[n * 16 + lrow][lkg * 8 + ks * 32];
        oacc[n] = MFMA16(ap, bvv, oacc[n]);
      }
  }
  // store partials (no normalization)
  const int idx = (((s * 4 + b) * 8 + h) * 8 + qt);
  float* ob = o_part + (size_t)idx * 4096;
  #pragma unroll
  for (int n = 0; n < 4; ++n)
    #pragma unroll
    for (int r = 0; r < 4; ++r) {
      int row = wv * 16 + lkg * 4 + r;
      ob[row * 64 + n * 16 + lrow] = oacc[n][r];
    }
  if (lrow == 0) {
    #pragma unroll
    for (int r = 0; r < 4; ++r) {
      int row = wv * 16 + lkg * 4 + r;
      ml_part[idx * 128 + row] = m_run[r];
      ml_part[idx * 128 + 64 + row] = l_run[r];
    }
  }
}

// combine split partials -> bf16 heavy attention output
__global__ __launch_bounds__(256)
void heavy_combine_kernel(const float* __restrict__ o_part, const float* __restrict__ ml_part,
                          bf16* __restrict__ oh) {
  const int qt = blockIdx.x, h = blockIdx.y, b = blockIdx.z;
  const int tid = threadIdx.x;
  const int row = tid >> 2, c0 = (tid & 3) * 16;
  int idx[4]; float m[4], l[4];
  #pragma unroll
  for (int s = 0; s < 4; ++s) {
    idx[s] = (((s * 4 + b) * 8 + h) * 8 + qt);
    m[s] = ml_part[idx[s] * 128 + row];
    l[s] = ml_part[idx[s] * 128 + 64 + row];
  }
  const float mstar = fmaxf(fmaxf(m[0], m[1]), fmaxf(m[2], m[3]));
  float wsum = 0.f, w[4];
  #pragma unroll
  for (int s = 0; s < 4; ++s) { w[s] = expf(m[s] - mstar); wsum += w[s] * l[s]; }
  const float inv = 1.0f / wsum;
  float o[16];
  #pragma unroll
  for (int i = 0; i < 16; ++i) o[i] = 0.f;
  #pragma unroll
  for (int s = 0; s < 4; ++s) {
    const fv4* op = (const fv4*)(o_part + (size_t)idx[s] * 4096 + row * 64 + c0);
    #pragma unroll
    for (int k = 0; k < 4; ++k) {
      fv4 v = op[k];
      #pragma unroll
      for (int j = 0; j < 4; ++j) o[k * 4 + j] += w[s] * v[j];
    }
  }
  const size_t ob = ((size_t)(b * 512 + qt * 64 + row)) * 512 + h * 64 + c0;
  bv8 pk[2];
  #pragma unroll
  for (int i = 0; i < 16; ++i) ((bf16*)pk)[i] = __float2bfloat16(o[i] * inv);
  *(bv8*)&oh[ob] = pk[0];
  *(bv8*)&oh[ob + 8] = pk[1];
}

// ---------------- launcher ----------------
extern "C" void kernel_launch(void* const* d_in, const int* in_sizes, int n_in,
                              void* d_out, int out_size, void* d_ws, size_t ws_size,
                              hipStream_t stream) {
  (void)in_sizes; (void)n_in; (void)out_size; (void)ws_size;
  const float* x     = (const float*)d_in[0];
  const float* ln_w  = (const float*)d_in[1];
  const float* ln_b  = (const float*)d_in[2];
  const float* Wqkv  = (const float*)d_in[3];
  const float* Woutl = (const float*)d_in[4];
  const float* rtq   = (const float*)d_in[5];
  const float* rtkv  = (const float*)d_in[6];
  const float* gamma = (const float*)d_in[7];
  const float* Wq    = (const float*)d_in[8];
  const float* Wkv   = (const float*)d_in[9];
  const float* Wouth = (const float*)d_in[10];
  const float* nkv   = (const float*)d_in[11];
  const float* nq    = (const float*)d_in[12];
  float* out = (float*)d_out;

  char* ws = (char*)d_ws;
  size_t off = 0;
  auto alloc = [&](size_t bytes) -> void* {
    void* p = ws + off;
    off = (off + bytes + 255) & ~(size_t)255;
    return p;
  };
  bf16* ln_bf    = (bf16*)alloc(16384ull * 1024 * 2);
  bf16* qkv_bf   = (bf16*)alloc(16384ull * 1536 * 2);
  bf16* ol_bf    = (bf16*)alloc(16384ull * 512 * 2);
  bf16* Wqkv_bf  = (bf16*)alloc(1536ull * 1024 * 2);
  bf16* Woutl_bf = (bf16*)alloc(1024ull * 512 * 2);
  bf16* Wq_bf    = (bf16*)alloc(512ull * 1024 * 2);
  bf16* Wkv_bf   = (bf16*)alloc(1024ull * 1024 * 2);
  bf16* Wouth_bf = (bf16*)alloc(1024ull * 512 * 2);
  double* s_d    = (double*)alloc(32768ull * 8);
  int* iq        = (int*)alloc(2048ull * 4);
  int* ikv       = (int*)alloc(4096ull * 4);
  int* posq      = (int*)alloc(16384ull * 4);
  bf16* xq_bf    = (bf16*)alloc(2048ull * 1024 * 2);
  bf16* xkv_bf   = (bf16*)alloc(4096ull * 1024 * 2);
  bf16* qh_bf    = (bf16*)alloc(2048ull * 512 * 2);
  bf16* kvh_bf   = (bf16*)alloc(4096ull * 1024 * 2);
  bf16* oh_bf    = (bf16*)alloc(2048ull * 512 * 2);
  float* heavy_f = (float*)alloc(2048ull * 1024 * 4);
  float* o_part  = (float*)alloc(4096ull * 4096 * 4);   // 4 splits x 1024 tiles x 64x64 f32
  float* ml_part = (float*)alloc(4096ull * 128 * 4);

  // fused weight casts (4M elements total)
  cast5_kernel<<<2048, 256, 0, stream>>>(Wqkv, Woutl, Wq, Wkv, Wouth,
                                         Wqkv_bf, Woutl_bf, Wq_bf, Wkv_bf, Wouth_bf);

  // fused LN + routing dots
  ln_sdot_kernel<<<16384, 256, 0, stream>>>(x, ln_w, ln_b, rtq, rtkv, ln_bf, s_d);

  // routing iterations + selection (single-wave register-resident iteration)
  hipMemsetAsync(posq, 0xFF, 16384 * 4, stream);
  route_sel_kernel<<<8, 256, 0, stream>>>(s_d, iq, ikv, posq);

  // light path
  gemm_bt<0><<<dim3(12, 128), 256, 0, stream>>>(ln_bf, Wqkv_bf, qkv_bf, 16384, 1536, 1024,
                                                nullptr, nullptr, nullptr);
  local_attn_kernel<<<dim3(64, 8, 4), 256, 0, stream>>>(qkv_bf, ol_bf);

  // heavy path
  gather_rms_kernel<<<6144, 256, 0, stream>>>(x, gamma, iq, ikv, xq_bf, xkv_bf);
  gemm_bt<0><<<dim3(4, 16), 256, 0, stream>>>(xq_bf, Wq_bf, qh_bf, 2048, 512, 1024,
                                              nullptr, nullptr, nullptr);
  gemm_bt<0><<<dim3(8, 32), 256, 0, stream>>>(xkv_bf, Wkv_bf, kvh_bf, 4096, 1024, 1024,
                                              nullptr, nullptr, nullptr);
  heavy_attn_split_kernel<<<dim3(8, 8, 16), 256, 0, stream>>>(qh_bf, kvh_bf, nkv, o_part, ml_part);
  heavy_combine_kernel<<<dim3(8, 8, 4), 256, 0, stream>>>(o_part, ml_part, oh_bf);
  gemm_bt<1><<<dim3(8, 16), 256, 0, stream>>>(oh_bf, Wouth_bf, heavy_f, 2048, 1024, 512,
                                              nullptr, nullptr, nullptr);

  // light output GEMM + fused combine (heavy scatter / null_q) -> d_out
  gemm_bt<2><<<dim3(8, 128), 256, 0, stream>>>(ol_bf, Woutl_bf, out, 16384, 1024, 512,
                                               posq, heavy_f, nq);
}